// Round 3
// baseline (1357.912 us; speedup 1.0000x reference)
//
#include <hip/hip_runtime.h>
#include <hip/hip_bf16.h>

// Problem constants
#define BROWS 8192      // B*N = 8*1024
#define DDIM 3
#define CDIM 64
#define KF 8192         // F = 2*C*C
#define NINV 512
#define NEQ 1024        // per head
#define NTOT 2560       // 512 + 1024 + 1024
#define BAS 16
#define UEQ 64

typedef float f32x4 __attribute__((ext_vector_type(4)));
typedef __bf16 bf16x8_t __attribute__((ext_vector_type(8)));
typedef __bf16 bf16x4_t __attribute__((ext_vector_type(4)));

// ---------------------------------------------------------------------------
// Kernel 1: per-row l2norm + Gram blocks -> feats bf16 [8192][8192]
// ---------------------------------------------------------------------------
__global__ __launch_bounds__(256) void feats_kernel(
    const float* __restrict__ t1, const float* __restrict__ t2,
    const float* __restrict__ u1, const float* __restrict__ u2,
    __hip_bfloat16* __restrict__ feats)
{
    const int row = blockIdx.x;
    const int tid = threadIdx.x;
    __shared__ float sT[2 * DDIM * CDIM];   // [head][d][c]
    __shared__ float sU[2 * DDIM * CDIM];   // scaled u

    const size_t base = (size_t)row * (DDIM * CDIM);
    if (tid < 192) {
        sT[tid]       = t1[base + tid];
        sT[192 + tid] = t2[base + tid];
        sU[tid]       = u1[base + tid];
        sU[192 + tid] = u2[base + tid];
    }
    __syncthreads();
    if (tid < 128) {
        const int h = tid >> 6, c = tid & 63;
        float* U = sU + h * 192;
        float sq = U[c] * U[c] + U[64 + c] * U[64 + c] + U[128 + c] * U[128 + c];
        float s = 1.0f / sqrtf(fmaxf(sq, 0.01f));
        U[c] *= s; U[64 + c] *= s; U[128 + c] *= s;
    }
    __syncthreads();
    // thread -> (h, i, j-half); writes 32 contiguous bf16
    const int h  = tid >> 7;            // 0..1
    const int i  = (tid >> 1) & 63;     // 0..63
    const int jh = (tid & 1) * 32;      // 0 or 32
    const float* T = sT + h * 192;
    const float* U = sU + h * 192;
    const float ti0 = T[i], ti1 = T[64 + i], ti2 = T[128 + i];
    __hip_bfloat16* dst = feats + (size_t)row * KF + h * 4096 + i * 64 + jh;
    #pragma unroll
    for (int q = 0; q < 8; ++q) {
        const int j = jh + q * 4;
        const float4 u0 = *reinterpret_cast<const float4*>(U + j);
        const float4 u1 = *reinterpret_cast<const float4*>(U + 64 + j);
        const float4 u2 = *reinterpret_cast<const float4*>(U + 128 + j);
        bf16x4_t v;
        v[0] = (__bf16)(ti0 * u0.x + ti1 * u1.x + ti2 * u2.x);
        v[1] = (__bf16)(ti0 * u0.y + ti1 * u1.y + ti2 * u2.y);
        v[2] = (__bf16)(ti0 * u0.z + ti1 * u1.z + ti2 * u2.z);
        v[3] = (__bf16)(ti0 * u0.w + ti1 * u1.w + ti2 * u2.w);
        *reinterpret_cast<bf16x4_t*>(dst + q * 4) = v;
    }
}

// ---------------------------------------------------------------------------
// Kernel 2: transpose+convert W (K x N fp32, three sources) -> WT bf16 [NTOT][KF]
// ---------------------------------------------------------------------------
__global__ __launch_bounds__(256) void wt_kernel(
    const float* __restrict__ W_inv, const float* __restrict__ W_eq,
    __hip_bfloat16* __restrict__ WT)
{
    __shared__ float tile[32][33];
    const int tid = threadIdx.x;
    const int tx = tid & 31;          // n within tile (load)
    const int ty = tid >> 5;          // 0..7
    const int n0 = blockIdx.x * 32;   // output column block (0..2559)
    const int k0 = blockIdx.y * 32;   // K block (0..8191)

    const float* src; int ldn, nl0;
    if (n0 < NINV)            { src = W_inv;                       ldn = NINV; nl0 = n0; }
    else if (n0 < NINV + NEQ) { src = W_eq;                        ldn = NEQ;  nl0 = n0 - NINV; }
    else                      { src = W_eq + (size_t)KF * NEQ;     ldn = NEQ;  nl0 = n0 - NINV - NEQ; }

    #pragma unroll
    for (int i = 0; i < 4; ++i) {
        int kl = ty + i * 8;
        tile[kl][tx] = src[(size_t)(k0 + kl) * ldn + nl0 + tx];
    }
    __syncthreads();
    // store phase: each thread packs 4 consecutive k for one n (8 B store)
    const int n_l = tid >> 3;
    const int k4  = (tid & 7) * 4;
    bf16x4_t v;
    #pragma unroll
    for (int q = 0; q < 4; ++q) v[q] = (__bf16)tile[k4 + q][n_l];
    *reinterpret_cast<bf16x4_t*>(&WT[(size_t)(n0 + n_l) * KF + k0 + k4]) = v;
}

// ---------------------------------------------------------------------------
// Kernel 3: concat BN params into [NTOT] arrays
// ---------------------------------------------------------------------------
__global__ __launch_bounds__(256) void params_kernel(
    const float* __restrict__ b_inv, const float* __restrict__ g_inv, const float* __restrict__ be_inv,
    const float* __restrict__ b_eq,  const float* __restrict__ g_eq,  const float* __restrict__ be_eq,
    float* __restrict__ cb, float* __restrict__ cg, float* __restrict__ cbe)
{
    int n = blockIdx.x * 256 + threadIdx.x;
    if (n >= NTOT) return;
    float b, g, be;
    if (n < NINV) { b = b_inv[n]; g = g_inv[n]; be = be_inv[n]; }
    else {
        int h = (n - NINV) / NEQ, nl = (n - NINV) % NEQ;
        b = b_eq[h * NEQ + nl]; g = g_eq[h * NEQ + nl]; be = be_eq[h * NEQ + nl];
    }
    cb[n] = b; cg[n] = g; cbe[n] = be;
}

// ---------------------------------------------------------------------------
// Kernel 4: LDS-free bf16 MFMA GEMM. No barriers; fragments loaded directly
// from global (L1/L2-hot k-slabs) with 2-stage register double-buffering.
// Compiler emits fine-grained dependency vmcnt waits (no barrier drain).
// ---------------------------------------------------------------------------
#define BM 128
#define BN 128

__global__ __launch_bounds__(256, 3) void gemm_kernel(
    const __hip_bfloat16* __restrict__ A,   // [BROWS][KF]
    const __hip_bfloat16* __restrict__ BT,  // [NTOT][KF]
    const float* __restrict__ cb, const float* __restrict__ cg, const float* __restrict__ cbe,
    float* __restrict__ out_inv,            // d_out: [BROWS][NINV]
    float* __restrict__ Yeq)                // ws:    [BROWS][2048]
{
    const int tid  = threadIdx.x;
    const int wave = tid >> 6;
    const int lane = tid & 63;

    // XCD-aware decode: xcd = b%8 owns 8 contiguous m-stripes, n fastest.
    const int b    = blockIdx.x;
    const int xcd  = b & 7;
    const int slot = b >> 3;            // 0..159
    const int n0   = (slot % 20) * BN;
    const int m0   = (xcd * 8 + slot / 20) * BM;

    const int wm = (wave & 1) * 64;
    const int wn = (wave >> 1) * 64;

    const int r    = lane & 15;         // row within 16
    const int koff = (lane >> 4) * 8;   // k element offset within 32-k tile

    const __hip_bfloat16* pA = A  + (size_t)(m0 + wm + r) * KF + koff;
    const __hip_bfloat16* pB = BT + (size_t)(n0 + wn + r) * KF + koff;

    f32x4 acc[4][4] = {};
    bf16x8_t a0[4], b0[4], a1[4], b1[4];

    #pragma unroll
    for (int t = 0; t < 4; ++t) {
        a0[t] = *reinterpret_cast<const bf16x8_t*>(pA + (size_t)t * 16 * KF);
        b0[t] = *reinterpret_cast<const bf16x8_t*>(pB + (size_t)t * 16 * KF);
    }

    for (int kt = 0; kt < KF; kt += 64) {
        // prefetch stage 1 (kt+32)
        #pragma unroll
        for (int t = 0; t < 4; ++t) {
            a1[t] = *reinterpret_cast<const bf16x8_t*>(pA + (size_t)t * 16 * KF + kt + 32);
            b1[t] = *reinterpret_cast<const bf16x8_t*>(pB + (size_t)t * 16 * KF + kt + 32);
        }
        // MFMA on stage 0
        #pragma unroll
        for (int mt = 0; mt < 4; ++mt)
            #pragma unroll
            for (int nt = 0; nt < 4; ++nt)
                acc[mt][nt] = __builtin_amdgcn_mfma_f32_16x16x32_bf16(
                    a0[mt], b0[nt], acc[mt][nt], 0, 0, 0);
        // prefetch stage 0 (kt+64)
        if (kt + 64 < KF) {
            #pragma unroll
            for (int t = 0; t < 4; ++t) {
                a0[t] = *reinterpret_cast<const bf16x8_t*>(pA + (size_t)t * 16 * KF + kt + 64);
                b0[t] = *reinterpret_cast<const bf16x8_t*>(pB + (size_t)t * 16 * KF + kt + 64);
            }
        }
        // MFMA on stage 1
        #pragma unroll
        for (int mt = 0; mt < 4; ++mt)
            #pragma unroll
            for (int nt = 0; nt < 4; ++nt)
                acc[mt][nt] = __builtin_amdgcn_mfma_f32_16x16x32_bf16(
                    a1[mt], b1[nt], acc[mt][nt], 0, 0, 0);
    }

    // epilogue: y = relu(g * (acc + b) / sqrt(1.001) + be)
    const float RSQ = 0.9995003746877732f;
    #pragma unroll
    for (int nt = 0; nt < 4; ++nt) {
        const int gn = n0 + wn + nt * 16 + (lane & 15);
        const float bbp = cb[gn];
        const float gg  = cg[gn] * RSQ;
        const float bep = cbe[gn];
        #pragma unroll
        for (int mt = 0; mt < 4; ++mt) {
            const int gmb = m0 + wm + mt * 16 + ((lane >> 4) << 2);
            #pragma unroll
            for (int rr = 0; rr < 4; ++rr) {
                float y = fmaxf(gg * (acc[mt][nt][rr] + bbp) + bep, 0.0f);
                const size_t gm = gmb + rr;
                if (n0 < NINV) out_inv[gm * NINV + gn] = y;
                else           Yeq[gm * 2048 + (gn - NINV)] = y;
            }
        }
    }
}

// ---------------------------------------------------------------------------
// Kernel 5: basis recombine
// ---------------------------------------------------------------------------
__global__ __launch_bounds__(128) void eqcomb_kernel(
    const float* __restrict__ Yeq,   // [BROWS][2048]
    const float* __restrict__ V1, const float* __restrict__ V2,
    float* __restrict__ out_eq)      // [BROWS][3][128]
{
    const int row = blockIdx.x;
    const int tid = threadIdx.x;     // 128
    __shared__ float sV[2][DDIM][BAS];
    if (tid < 96) {
        const int h = tid / 48, rem = tid % 48;
        const float* V = h ? V2 : V1;
        sV[h][rem / BAS][rem % BAS] = V[(size_t)row * (DDIM * BAS) + rem];
    }
    __syncthreads();
    const int l = tid >> 6, u = tid & 63;
    const float4* y4 = reinterpret_cast<const float4*>(
        Yeq + (size_t)row * 2048 + l * 1024 + u * BAS);
    float a0 = 0.f, a1 = 0.f, a2 = 0.f;
    #pragma unroll
    for (int q = 0; q < 4; ++q) {
        float4 w = y4[q];
        const float* v0 = sV[l][0] + q * 4;
        const float* v1 = sV[l][1] + q * 4;
        const float* v2 = sV[l][2] + q * 4;
        a0 += w.x * v0[0] + w.y * v0[1] + w.z * v0[2] + w.w * v0[3];
        a1 += w.x * v1[0] + w.y * v1[1] + w.z * v1[2] + w.w * v1[3];
        a2 += w.x * v2[0] + w.y * v2[1] + w.z * v2[2] + w.w * v2[3];
    }
    float* o = out_eq + (size_t)row * (DDIM * 128);
    o[0 * 128 + l * 64 + u] = a0;
    o[1 * 128 + l * 64 + u] = a1;
    o[2 * 128 + l * 64 + u] = a2;
}

// ---------------------------------------------------------------------------
extern "C" void kernel_launch(void* const* d_in, const int* in_sizes, int n_in,
                              void* d_out, int out_size, void* d_ws, size_t ws_size,
                              hipStream_t stream) {
    const float* t1    = (const float*)d_in[0];
    const float* t2    = (const float*)d_in[1];
    const float* u1    = (const float*)d_in[2];
    const float* u2    = (const float*)d_in[3];
    const float* V1    = (const float*)d_in[4];
    const float* V2    = (const float*)d_in[5];
    const float* W_inv = (const float*)d_in[6];
    const float* b_inv = (const float*)d_in[7];
    const float* g_inv = (const float*)d_in[8];
    const float* be_inv= (const float*)d_in[9];
    const float* W_eq  = (const float*)d_in[10];
    const float* b_eq  = (const float*)d_in[11];
    const float* g_eq  = (const float*)d_in[12];
    const float* be_eq = (const float*)d_in[13];
    float* out = (float*)d_out;

    // workspace layout (bytes)
    char* ws = (char*)d_ws;
    __hip_bfloat16* feats = (__hip_bfloat16*)(ws);                       // 134,217,728
    __hip_bfloat16* WT    = (__hip_bfloat16*)(ws + 134217728);           //  41,943,040
    float*          Yeq   = (float*)(ws + 176160768);                    //  67,108,864
    float*          cb    = (float*)(ws + 243269632);
    float*          cg    = (float*)(ws + 243279872);
    float*          cbe   = (float*)(ws + 243290112);

    float* out_inv = out;                                  // [8192][512]
    float* out_eq  = out + (size_t)BROWS * NINV;           // [8192][3][128]

    hipLaunchKernelGGL(feats_kernel, dim3(BROWS), dim3(256), 0, stream,
                       t1, t2, u1, u2, feats);
    hipLaunchKernelGGL(wt_kernel, dim3(NTOT / 32, KF / 32), dim3(256), 0, stream,
                       W_inv, W_eq, WT);
    hipLaunchKernelGGL(params_kernel, dim3((NTOT + 255) / 256), dim3(256), 0, stream,
                       b_inv, g_inv, be_inv, b_eq, g_eq, be_eq, cb, cg, cbe);
    hipLaunchKernelGGL(gemm_kernel, dim3((NTOT / BN) * (BROWS / BM)), dim3(256), 0, stream,
                       feats, WT, cb, cg, cbe, out_inv, Yeq);
    hipLaunchKernelGGL(eqcomb_kernel, dim3(BROWS), dim3(128), 0, stream,
                       Yeq, V1, V2, out_eq);
}

// Round 4
// 828.835 us; speedup vs baseline: 1.6383x; 1.6383x over previous
//
#include <hip/hip_runtime.h>
#include <hip/hip_bf16.h>

// Problem constants
#define BROWS 8192      // B*N = 8*1024
#define DDIM 3
#define CDIM 64
#define KF 8192         // F = 2*C*C
#define NINV 512
#define NEQ 1024        // per head
#define NTOT 2560       // 512 + 1024 + 1024
#define BAS 16
#define UEQ 64

typedef float f32x4 __attribute__((ext_vector_type(4)));
typedef __bf16 bf16x8_t __attribute__((ext_vector_type(8)));
typedef __bf16 bf16x4_t __attribute__((ext_vector_type(4)));

__device__ __forceinline__ void async_copy16(const void* g, void* l) {
    __builtin_amdgcn_global_load_lds(
        (__attribute__((address_space(1))) void*)(g),
        (__attribute__((address_space(3))) void*)(l), 16, 0, 0);
}

// ---------------------------------------------------------------------------
// Kernel 1: per-row l2norm + Gram blocks -> feats bf16 [8192][8192]
// ---------------------------------------------------------------------------
__global__ __launch_bounds__(256) void feats_kernel(
    const float* __restrict__ t1, const float* __restrict__ t2,
    const float* __restrict__ u1, const float* __restrict__ u2,
    __hip_bfloat16* __restrict__ feats)
{
    const int row = blockIdx.x;
    const int tid = threadIdx.x;
    __shared__ float sT[2 * DDIM * CDIM];   // [head][d][c]
    __shared__ float sU[2 * DDIM * CDIM];   // scaled u

    const size_t base = (size_t)row * (DDIM * CDIM);
    if (tid < 192) {
        sT[tid]       = t1[base + tid];
        sT[192 + tid] = t2[base + tid];
        sU[tid]       = u1[base + tid];
        sU[192 + tid] = u2[base + tid];
    }
    __syncthreads();
    if (tid < 128) {
        const int h = tid >> 6, c = tid & 63;
        float* U = sU + h * 192;
        float sq = U[c] * U[c] + U[64 + c] * U[64 + c] + U[128 + c] * U[128 + c];
        float s = 1.0f / sqrtf(fmaxf(sq, 0.01f));
        U[c] *= s; U[64 + c] *= s; U[128 + c] *= s;
    }
    __syncthreads();
    // thread -> (h, i, j-half); writes 32 contiguous bf16
    const int h  = tid >> 7;            // 0..1
    const int i  = (tid >> 1) & 63;     // 0..63
    const int jh = (tid & 1) * 32;      // 0 or 32
    const float* T = sT + h * 192;
    const float* U = sU + h * 192;
    const float ti0 = T[i], ti1 = T[64 + i], ti2 = T[128 + i];
    __hip_bfloat16* dst = feats + (size_t)row * KF + h * 4096 + i * 64 + jh;
    #pragma unroll
    for (int q = 0; q < 8; ++q) {
        const int j = jh + q * 4;
        const float4 u0 = *reinterpret_cast<const float4*>(U + j);
        const float4 u1 = *reinterpret_cast<const float4*>(U + 64 + j);
        const float4 u2 = *reinterpret_cast<const float4*>(U + 128 + j);
        bf16x4_t v;
        v[0] = (__bf16)(ti0 * u0.x + ti1 * u1.x + ti2 * u2.x);
        v[1] = (__bf16)(ti0 * u0.y + ti1 * u1.y + ti2 * u2.y);
        v[2] = (__bf16)(ti0 * u0.z + ti1 * u1.z + ti2 * u2.z);
        v[3] = (__bf16)(ti0 * u0.w + ti1 * u1.w + ti2 * u2.w);
        *reinterpret_cast<bf16x4_t*>(dst + q * 4) = v;
    }
}

// ---------------------------------------------------------------------------
// Kernel 2: transpose+convert W (K x N fp32, three sources) -> WT bf16 [NTOT][KF]
// ---------------------------------------------------------------------------
__global__ __launch_bounds__(256) void wt_kernel(
    const float* __restrict__ W_inv, const float* __restrict__ W_eq,
    __hip_bfloat16* __restrict__ WT)
{
    __shared__ float tile[32][33];
    const int tid = threadIdx.x;
    const int tx = tid & 31;          // n within tile (load)
    const int ty = tid >> 5;          // 0..7
    const int n0 = blockIdx.x * 32;   // output column block (0..2559)
    const int k0 = blockIdx.y * 32;   // K block (0..8191)

    const float* src; int ldn, nl0;
    if (n0 < NINV)            { src = W_inv;                       ldn = NINV; nl0 = n0; }
    else if (n0 < NINV + NEQ) { src = W_eq;                        ldn = NEQ;  nl0 = n0 - NINV; }
    else                      { src = W_eq + (size_t)KF * NEQ;     ldn = NEQ;  nl0 = n0 - NINV - NEQ; }

    #pragma unroll
    for (int i = 0; i < 4; ++i) {
        int kl = ty + i * 8;
        tile[kl][tx] = src[(size_t)(k0 + kl) * ldn + nl0 + tx];
    }
    __syncthreads();
    // store phase: each thread packs 4 consecutive k for one n (8 B store)
    const int n_l = tid >> 3;
    const int k4  = (tid & 7) * 4;
    bf16x4_t v;
    #pragma unroll
    for (int q = 0; q < 4; ++q) v[q] = (__bf16)tile[k4 + q][n_l];
    *reinterpret_cast<bf16x4_t*>(&WT[(size_t)(n0 + n_l) * KF + k0 + k4]) = v;
}

// ---------------------------------------------------------------------------
// Kernel 3: concat BN params into [NTOT] arrays
// ---------------------------------------------------------------------------
__global__ __launch_bounds__(256) void params_kernel(
    const float* __restrict__ b_inv, const float* __restrict__ g_inv, const float* __restrict__ be_inv,
    const float* __restrict__ b_eq,  const float* __restrict__ g_eq,  const float* __restrict__ be_eq,
    float* __restrict__ cb, float* __restrict__ cg, float* __restrict__ cbe)
{
    int n = blockIdx.x * 256 + threadIdx.x;
    if (n >= NTOT) return;
    float b, g, be;
    if (n < NINV) { b = b_inv[n]; g = g_inv[n]; be = be_inv[n]; }
    else {
        int h = (n - NINV) / NEQ, nl = (n - NINV) % NEQ;
        b = b_eq[h * NEQ + nl]; g = g_eq[h * NEQ + nl]; be = be_eq[h * NEQ + nl];
    }
    cb[n] = b; cg[n] = g; cbe[n] = be;
}

// ---------------------------------------------------------------------------
// Kernel 4: bf16 MFMA GEMM, 3-stage LDS pipeline (prefetch distance 2),
//           chunk swizzle (0 bank conflicts) + XCD swizzle.
// ---------------------------------------------------------------------------
#define BM 128
#define BN 128
#define BK 32

__global__ __launch_bounds__(256) void gemm_kernel(
    const __hip_bfloat16* __restrict__ A,   // [BROWS][KF]
    const __hip_bfloat16* __restrict__ BT,  // [NTOT][KF]
    const float* __restrict__ cb, const float* __restrict__ cg, const float* __restrict__ cbe,
    float* __restrict__ out_inv,            // d_out: [BROWS][NINV]
    float* __restrict__ Yeq)                // ws:    [BROWS][2048]
{
    __shared__ alignas(16) __hip_bfloat16 As[3][BM * BK];  // 3 x 8 KB
    __shared__ alignas(16) __hip_bfloat16 Bs[3][BN * BK];  // 3 x 8 KB

    const int tid  = threadIdx.x;
    const int wave = tid >> 6;
    const int lane = tid & 63;

    // XCD-aware decode: xcd = b%8 owns 8 contiguous m-stripes, n fastest.
    const int b    = blockIdx.x;
    const int xcd  = b & 7;
    const int slot = b >> 3;            // 0..159
    const int n0   = (slot % 20) * BN;
    const int m0   = (xcd * 8 + slot / 20) * BM;

    const int wm = (wave & 1) * 64;
    const int wn = (wave >> 1) * 64;

    f32x4 acc[4][4] = {};

    const int rpart = lane & 3;          // phys 16B chunk slot within 64B row
    const int rsub  = lane >> 2;         // row within a 16-row group

    // staging: lane L serves (rowLocal, phys chunk rpart); global source uses
    // the swizzled logical chunk: log = (rpart - (rowLocal>>1)) & 3
    const int rowL0 = wave * 32 + rsub;
    const int rowL1 = rowL0 + 16;
    const int ck0 = ((rpart - (rowL0 >> 1)) & 3) * 8;   // elements
    const int ck1 = ((rpart - (rowL1 >> 1)) & 3) * 8;
    const __hip_bfloat16* gA0 = A  + (size_t)(m0 + rowL0) * KF + ck0;
    const __hip_bfloat16* gA1 = A  + (size_t)(m0 + rowL1) * KF + ck1;
    const __hip_bfloat16* gB0 = BT + (size_t)(n0 + rowL0) * KF + ck0;
    const __hip_bfloat16* gB1 = BT + (size_t)(n0 + rowL1) * KF + ck1;

    // ds_read side: phys chunk = (log chunk + (row>>1)) & 3
    const int arow  = wm + (lane & 15);
    const int brow  = wn + (lane & 15);
    const int achnk = (((lane >> 4) + (arow >> 1)) & 3) * 8;
    const int bchnk = (((lane >> 4) + (brow >> 1)) & 3) * 8;

    const int stoff = wave * 2048 + lane * 16;

    // prologue: tiles 0,1 -> buffers 0,1
    #pragma unroll
    for (int t = 0; t < 2; ++t) {
        const size_t ko = (size_t)t * BK;
        char* dA = (char*)&As[t][0] + stoff;
        char* dB = (char*)&Bs[t][0] + stoff;
        async_copy16(gA0 + ko, dA);
        async_copy16(gA1 + ko, dA + 1024);
        async_copy16(gB0 + ko, dB);
        async_copy16(gB1 + ko, dB + 1024);
    }

    const int ITERS = KF / BK;   // 256
    int bcur = 0;
    for (int i = 0; i < ITERS; ++i) {
        if (i + 2 < ITERS) {
            int bpre = bcur + 2; if (bpre >= 3) bpre -= 3;
            const size_t ko = (size_t)(i + 2) * BK;
            char* dA = (char*)&As[bpre][0] + stoff;
            char* dB = (char*)&Bs[bpre][0] + stoff;
            async_copy16(gA0 + ko, dA);
            async_copy16(gA1 + ko, dA + 1024);
            async_copy16(gB0 + ko, dB);
            async_copy16(gB1 + ko, dB + 1024);
            // 12 outstanding; wait until only the 8 newer remain -> tile i done
            asm volatile("s_waitcnt vmcnt(8)" ::: "memory");
        } else if (i + 1 < ITERS) {
            asm volatile("s_waitcnt vmcnt(4)" ::: "memory");
        } else {
            asm volatile("s_waitcnt vmcnt(0)" ::: "memory");
        }
        __builtin_amdgcn_s_barrier();
        asm volatile("" ::: "memory");

        bf16x8_t a[4], bb[4];
        #pragma unroll
        for (int mt = 0; mt < 4; ++mt)
            a[mt] = *reinterpret_cast<const bf16x8_t*>(
                &As[bcur][(wm + mt * 16 + (lane & 15)) * BK + achnk]);
        #pragma unroll
        for (int nt = 0; nt < 4; ++nt)
            bb[nt] = *reinterpret_cast<const bf16x8_t*>(
                &Bs[bcur][(wn + nt * 16 + (lane & 15)) * BK + bchnk]);

        #pragma unroll
        for (int mt = 0; mt < 4; ++mt)
            #pragma unroll
            for (int nt = 0; nt < 4; ++nt)
                acc[mt][nt] = __builtin_amdgcn_mfma_f32_16x16x32_bf16(
                    a[mt], bb[nt], acc[mt][nt], 0, 0, 0);

        asm volatile("" ::: "memory");
        __builtin_amdgcn_s_barrier();
        asm volatile("" ::: "memory");

        bcur = (bcur + 1 == 3) ? 0 : bcur + 1;
    }

    // epilogue: y = relu(g * (acc + b) / sqrt(1.001) + be)
    const float RSQ = 0.9995003746877732f;
    #pragma unroll
    for (int nt = 0; nt < 4; ++nt) {
        const int gn = n0 + wn + nt * 16 + (lane & 15);
        const float bbp = cb[gn];
        const float gg  = cg[gn] * RSQ;
        const float bep = cbe[gn];
        #pragma unroll
        for (int mt = 0; mt < 4; ++mt) {
            const int gmb = m0 + wm + mt * 16 + ((lane >> 4) << 2);
            #pragma unroll
            for (int rr = 0; rr < 4; ++rr) {
                float y = fmaxf(gg * (acc[mt][nt][rr] + bbp) + bep, 0.0f);
                const size_t gm = gmb + rr;
                if (n0 < NINV) out_inv[gm * NINV + gn] = y;
                else           Yeq[gm * 2048 + (gn - NINV)] = y;
            }
        }
    }
}

// ---------------------------------------------------------------------------
// Kernel 5: basis recombine
// ---------------------------------------------------------------------------
__global__ __launch_bounds__(128) void eqcomb_kernel(
    const float* __restrict__ Yeq,   // [BROWS][2048]
    const float* __restrict__ V1, const float* __restrict__ V2,
    float* __restrict__ out_eq)      // [BROWS][3][128]
{
    const int row = blockIdx.x;
    const int tid = threadIdx.x;     // 128
    __shared__ float sV[2][DDIM][BAS];
    if (tid < 96) {
        const int h = tid / 48, rem = tid % 48;
        const float* V = h ? V2 : V1;
        sV[h][rem / BAS][rem % BAS] = V[(size_t)row * (DDIM * BAS) + rem];
    }
    __syncthreads();
    const int l = tid >> 6, u = tid & 63;
    const float4* y4 = reinterpret_cast<const float4*>(
        Yeq + (size_t)row * 2048 + l * 1024 + u * BAS);
    float a0 = 0.f, a1 = 0.f, a2 = 0.f;
    #pragma unroll
    for (int q = 0; q < 4; ++q) {
        float4 w = y4[q];
        const float* v0 = sV[l][0] + q * 4;
        const float* v1 = sV[l][1] + q * 4;
        const float* v2 = sV[l][2] + q * 4;
        a0 += w.x * v0[0] + w.y * v0[1] + w.z * v0[2] + w.w * v0[3];
        a1 += w.x * v1[0] + w.y * v1[1] + w.z * v1[2] + w.w * v1[3];
        a2 += w.x * v2[0] + w.y * v2[1] + w.z * v2[2] + w.w * v2[3];
    }
    float* o = out_eq + (size_t)row * (DDIM * 128);
    o[0 * 128 + l * 64 + u] = a0;
    o[1 * 128 + l * 64 + u] = a1;
    o[2 * 128 + l * 64 + u] = a2;
}

// ---------------------------------------------------------------------------
extern "C" void kernel_launch(void* const* d_in, const int* in_sizes, int n_in,
                              void* d_out, int out_size, void* d_ws, size_t ws_size,
                              hipStream_t stream) {
    const float* t1    = (const float*)d_in[0];
    const float* t2    = (const float*)d_in[1];
    const float* u1    = (const float*)d_in[2];
    const float* u2    = (const float*)d_in[3];
    const float* V1    = (const float*)d_in[4];
    const float* V2    = (const float*)d_in[5];
    const float* W_inv = (const float*)d_in[6];
    const float* b_inv = (const float*)d_in[7];
    const float* g_inv = (const float*)d_in[8];
    const float* be_inv= (const float*)d_in[9];
    const float* W_eq  = (const float*)d_in[10];
    const float* b_eq  = (const float*)d_in[11];
    const float* g_eq  = (const float*)d_in[12];
    const float* be_eq = (const float*)d_in[13];
    float* out = (float*)d_out;

    // workspace layout (bytes)
    char* ws = (char*)d_ws;
    __hip_bfloat16* feats = (__hip_bfloat16*)(ws);                       // 134,217,728
    __hip_bfloat16* WT    = (__hip_bfloat16*)(ws + 134217728);           //  41,943,040
    float*          Yeq   = (float*)(ws + 176160768);                    //  67,108,864
    float*          cb    = (float*)(ws + 243269632);
    float*          cg    = (float*)(ws + 243279872);
    float*          cbe   = (float*)(ws + 243290112);

    float* out_inv = out;                                  // [8192][512]
    float* out_eq  = out + (size_t)BROWS * NINV;           // [8192][3][128]

    hipLaunchKernelGGL(feats_kernel, dim3(BROWS), dim3(256), 0, stream,
                       t1, t2, u1, u2, feats);
    hipLaunchKernelGGL(wt_kernel, dim3(NTOT / 32, KF / 32), dim3(256), 0, stream,
                       W_inv, W_eq, WT);
    hipLaunchKernelGGL(params_kernel, dim3((NTOT + 255) / 256), dim3(256), 0, stream,
                       b_inv, g_inv, be_inv, b_eq, g_eq, be_eq, cb, cg, cbe);
    hipLaunchKernelGGL(gemm_kernel, dim3((NTOT / BN) * (BROWS / BM)), dim3(256), 0, stream,
                       feats, WT, cb, cg, cbe, out_inv, Yeq);
    hipLaunchKernelGGL(eqcomb_kernel, dim3(BROWS), dim3(128), 0, stream,
                       Yeq, V1, V2, out_eq);
}

// Round 5
// 734.834 us; speedup vs baseline: 1.8479x; 1.1279x over previous
//
#include <hip/hip_runtime.h>
#include <hip/hip_bf16.h>

// Problem constants
#define BROWS 8192      // B*N = 8*1024
#define DDIM 3
#define CDIM 64
#define KF 8192         // F = 2*C*C
#define NINV 512
#define NEQ 1024        // per head
#define NTOT 2560       // 512 + 1024 + 1024
#define BAS 16
#define UEQ 64

typedef float f32x4 __attribute__((ext_vector_type(4)));
typedef __bf16 bf16x8_t __attribute__((ext_vector_type(8)));
typedef __bf16 bf16x4_t __attribute__((ext_vector_type(4)));

__device__ __forceinline__ void async_copy16(const void* g, void* l) {
    __builtin_amdgcn_global_load_lds(
        (__attribute__((address_space(1))) void*)(g),
        (__attribute__((address_space(3))) void*)(l), 16, 0, 0);
}

// ---------------------------------------------------------------------------
// Kernel 1: per-row l2norm + Gram blocks -> feats bf16 [8192][8192]
// ---------------------------------------------------------------------------
__global__ __launch_bounds__(256) void feats_kernel(
    const float* __restrict__ t1, const float* __restrict__ t2,
    const float* __restrict__ u1, const float* __restrict__ u2,
    __hip_bfloat16* __restrict__ feats)
{
    const int row = blockIdx.x;
    const int tid = threadIdx.x;
    __shared__ float sT[2 * DDIM * CDIM];   // [head][d][c]
    __shared__ float sU[2 * DDIM * CDIM];   // scaled u

    const size_t base = (size_t)row * (DDIM * CDIM);
    if (tid < 192) {
        sT[tid]       = t1[base + tid];
        sT[192 + tid] = t2[base + tid];
        sU[tid]       = u1[base + tid];
        sU[192 + tid] = u2[base + tid];
    }
    __syncthreads();
    if (tid < 128) {
        const int h = tid >> 6, c = tid & 63;
        float* U = sU + h * 192;
        float sq = U[c] * U[c] + U[64 + c] * U[64 + c] + U[128 + c] * U[128 + c];
        float s = 1.0f / sqrtf(fmaxf(sq, 0.01f));
        U[c] *= s; U[64 + c] *= s; U[128 + c] *= s;
    }
    __syncthreads();
    // thread -> (h, i, j-half); writes 32 contiguous bf16
    const int h  = tid >> 7;            // 0..1
    const int i  = (tid >> 1) & 63;     // 0..63
    const int jh = (tid & 1) * 32;      // 0 or 32
    const float* T = sT + h * 192;
    const float* U = sU + h * 192;
    const float ti0 = T[i], ti1 = T[64 + i], ti2 = T[128 + i];
    __hip_bfloat16* dst = feats + (size_t)row * KF + h * 4096 + i * 64 + jh;
    #pragma unroll
    for (int q = 0; q < 8; ++q) {
        const int j = jh + q * 4;
        const float4 u0 = *reinterpret_cast<const float4*>(U + j);
        const float4 u1 = *reinterpret_cast<const float4*>(U + 64 + j);
        const float4 u2 = *reinterpret_cast<const float4*>(U + 128 + j);
        bf16x4_t v;
        v[0] = (__bf16)(ti0 * u0.x + ti1 * u1.x + ti2 * u2.x);
        v[1] = (__bf16)(ti0 * u0.y + ti1 * u1.y + ti2 * u2.y);
        v[2] = (__bf16)(ti0 * u0.z + ti1 * u1.z + ti2 * u2.z);
        v[3] = (__bf16)(ti0 * u0.w + ti1 * u1.w + ti2 * u2.w);
        *reinterpret_cast<bf16x4_t*>(dst + q * 4) = v;
    }
}

// ---------------------------------------------------------------------------
// Kernel 2: transpose+convert W (K x N fp32, three sources) -> WT bf16 [NTOT][KF]
// ---------------------------------------------------------------------------
__global__ __launch_bounds__(256) void wt_kernel(
    const float* __restrict__ W_inv, const float* __restrict__ W_eq,
    __hip_bfloat16* __restrict__ WT)
{
    __shared__ float tile[32][33];
    const int tid = threadIdx.x;
    const int tx = tid & 31;          // n within tile (load)
    const int ty = tid >> 5;          // 0..7
    const int n0 = blockIdx.x * 32;   // output column block (0..2559)
    const int k0 = blockIdx.y * 32;   // K block (0..8191)

    const float* src; int ldn, nl0;
    if (n0 < NINV)            { src = W_inv;                       ldn = NINV; nl0 = n0; }
    else if (n0 < NINV + NEQ) { src = W_eq;                        ldn = NEQ;  nl0 = n0 - NINV; }
    else                      { src = W_eq + (size_t)KF * NEQ;     ldn = NEQ;  nl0 = n0 - NINV - NEQ; }

    #pragma unroll
    for (int i = 0; i < 4; ++i) {
        int kl = ty + i * 8;
        tile[kl][tx] = src[(size_t)(k0 + kl) * ldn + nl0 + tx];
    }
    __syncthreads();
    // store phase: each thread packs 4 consecutive k for one n (8 B store)
    const int n_l = tid >> 3;
    const int k4  = (tid & 7) * 4;
    bf16x4_t v;
    #pragma unroll
    for (int q = 0; q < 4; ++q) v[q] = (__bf16)tile[k4 + q][n_l];
    *reinterpret_cast<bf16x4_t*>(&WT[(size_t)(n0 + n_l) * KF + k0 + k4]) = v;
}

// ---------------------------------------------------------------------------
// Kernel 3: concat BN params into [NTOT] arrays
// ---------------------------------------------------------------------------
__global__ __launch_bounds__(256) void params_kernel(
    const float* __restrict__ b_inv, const float* __restrict__ g_inv, const float* __restrict__ be_inv,
    const float* __restrict__ b_eq,  const float* __restrict__ g_eq,  const float* __restrict__ be_eq,
    float* __restrict__ cb, float* __restrict__ cg, float* __restrict__ cbe)
{
    int n = blockIdx.x * 256 + threadIdx.x;
    if (n >= NTOT) return;
    float b, g, be;
    if (n < NINV) { b = b_inv[n]; g = g_inv[n]; be = be_inv[n]; }
    else {
        int h = (n - NINV) / NEQ, nl = (n - NINV) % NEQ;
        b = b_eq[h * NEQ + nl]; g = g_eq[h * NEQ + nl]; be = be_eq[h * NEQ + nl];
    }
    cb[n] = b; cg[n] = g; cbe[n] = be;
}

// ---------------------------------------------------------------------------
// Kernel 4: bf16 MFMA GEMM. 128 threads = 2 waves; wave tile 64x128 ->
// 32 MFMA per barrier-pair (AITER-like density) with only 32 KB LDS.
// Double-buffered, distance-1 prefetch, static buffer indices, chunk+XCD swizzle.
// ---------------------------------------------------------------------------
#define BM 128
#define BN 128
#define BK 32

struct GemmCtx {
    const __hip_bfloat16* gA[4];
    const __hip_bfloat16* gB[4];
    __hip_bfloat16* As[2];
    __hip_bfloat16* Bs[2];
    int stoff;   // byte offset within buffer for staging dest (c=0)
    int chnk;    // element offset of 16B chunk for ds_read
    int wm, lane;
};

__device__ __forceinline__ void issue8(const GemmCtx& c, int buf, int k) {
    #pragma unroll
    for (int j = 0; j < 4; ++j)
        async_copy16(c.gA[j] + k, (char*)c.As[buf] + c.stoff + j * 1024);
    #pragma unroll
    for (int j = 0; j < 4; ++j)
        async_copy16(c.gB[j] + k, (char*)c.Bs[buf] + c.stoff + j * 1024);
}

__device__ __forceinline__ void compute32(const GemmCtx& c, int buf, f32x4 (&acc)[4][8]) {
    const int l15 = c.lane & 15;
    bf16x8_t a[4], b[8];
    #pragma unroll
    for (int mt = 0; mt < 4; ++mt)
        a[mt] = *reinterpret_cast<const bf16x8_t*>(
            &c.As[buf][(c.wm + mt * 16 + l15) * BK + c.chnk]);
    #pragma unroll
    for (int nt = 0; nt < 8; ++nt)
        b[nt] = *reinterpret_cast<const bf16x8_t*>(
            &c.Bs[buf][(nt * 16 + l15) * BK + c.chnk]);
    #pragma unroll
    for (int mt = 0; mt < 4; ++mt)
        #pragma unroll
        for (int nt = 0; nt < 8; ++nt)
            acc[mt][nt] = __builtin_amdgcn_mfma_f32_16x16x32_bf16(
                a[mt], b[nt], acc[mt][nt], 0, 0, 0);
}

__global__ __launch_bounds__(128, 2) void gemm_kernel(
    const __hip_bfloat16* __restrict__ A,   // [BROWS][KF]
    const __hip_bfloat16* __restrict__ BT,  // [NTOT][KF]
    const float* __restrict__ cb, const float* __restrict__ cg, const float* __restrict__ cbe,
    float* __restrict__ out_inv,            // d_out: [BROWS][NINV]
    float* __restrict__ Yeq)                // ws:    [BROWS][2048]
{
    __shared__ alignas(16) __hip_bfloat16 AsBuf[2][BM * BK];  // 2 x 8 KB
    __shared__ alignas(16) __hip_bfloat16 BsBuf[2][BN * BK];  // 2 x 8 KB

    const int tid  = threadIdx.x;
    const int wave = tid >> 6;
    const int lane = tid & 63;

    // XCD-aware decode: xcd = b%8 owns 8 contiguous m-stripes, n fastest.
    const int b    = blockIdx.x;
    const int xcd  = b & 7;
    const int slot = b >> 3;            // 0..159
    const int n0   = (slot % 20) * BN;
    const int m0   = (xcd * 8 + slot / 20) * BM;

    GemmCtx c;
    c.wm   = wave * 64;
    c.lane = lane;
    c.As[0] = &AsBuf[0][0]; c.As[1] = &AsBuf[1][0];
    c.Bs[0] = &BsBuf[0][0]; c.Bs[1] = &BsBuf[1][0];

    const int rsub  = lane >> 2;         // row within a 16-row group
    const int rpart = lane & 3;          // phys 16B chunk
    c.stoff = wave * 4096 + lane * 16;
    #pragma unroll
    for (int j = 0; j < 4; ++j) {
        const int row = wave * 64 + j * 16 + rsub;
        const int ck  = ((rpart - (row >> 1)) & 3) * 8;   // logical chunk (elements)
        c.gA[j] = A  + (size_t)(m0 + row) * KF + ck;
        c.gB[j] = BT + (size_t)(n0 + row) * KF + ck;
    }
    // ds_read phys chunk: (logical + (row>>1)) & 3; row = *16*t + (lane&15) so
    // the *16 part is ≡0 mod 4 after >>1 — chunk is tile-independent:
    c.chnk = (((lane >> 4) + ((lane & 15) >> 1)) & 3) * 8;

    f32x4 acc[4][8] = {};

    issue8(c, 0, 0);   // prologue: tile 0 -> buf 0

    for (int kt = 0; kt < KF; kt += 64) {
        // phase A: compute buf0 @ kt, prefetch buf1 @ kt+32 (always valid)
        issue8(c, 1, kt + 32);
        asm volatile("s_waitcnt vmcnt(8)" ::: "memory");
        __builtin_amdgcn_s_barrier();
        asm volatile("" ::: "memory");
        compute32(c, 0, acc);
        asm volatile("" ::: "memory");
        __builtin_amdgcn_s_barrier();

        // phase B: compute buf1 @ kt+32, prefetch buf0 @ kt+64
        if (kt + 64 < KF) {
            issue8(c, 0, kt + 64);
            asm volatile("s_waitcnt vmcnt(8)" ::: "memory");
        } else {
            asm volatile("s_waitcnt vmcnt(0)" ::: "memory");
        }
        __builtin_amdgcn_s_barrier();
        asm volatile("" ::: "memory");
        compute32(c, 1, acc);
        asm volatile("" ::: "memory");
        __builtin_amdgcn_s_barrier();
    }

    // epilogue: y = relu(g * (acc + b) / sqrt(1.001) + be)
    const float RSQ = 0.9995003746877732f;
    #pragma unroll
    for (int nt = 0; nt < 8; ++nt) {
        const int gn = n0 + nt * 16 + (lane & 15);
        const float bbp = cb[gn];
        const float gg  = cg[gn] * RSQ;
        const float bep = cbe[gn];
        #pragma unroll
        for (int mt = 0; mt < 4; ++mt) {
            const int gmb = m0 + c.wm + mt * 16 + ((lane >> 4) << 2);
            #pragma unroll
            for (int rr = 0; rr < 4; ++rr) {
                float y = fmaxf(gg * (acc[mt][nt][rr] + bbp) + bep, 0.0f);
                const size_t gm = gmb + rr;
                if (n0 < NINV) out_inv[gm * NINV + gn] = y;
                else           Yeq[gm * 2048 + (gn - NINV)] = y;
            }
        }
    }
}

// ---------------------------------------------------------------------------
// Kernel 5: basis recombine
// ---------------------------------------------------------------------------
__global__ __launch_bounds__(128) void eqcomb_kernel(
    const float* __restrict__ Yeq,   // [BROWS][2048]
    const float* __restrict__ V1, const float* __restrict__ V2,
    float* __restrict__ out_eq)      // [BROWS][3][128]
{
    const int row = blockIdx.x;
    const int tid = threadIdx.x;     // 128
    __shared__ float sV[2][DDIM][BAS];
    if (tid < 96) {
        const int h = tid / 48, rem = tid % 48;
        const float* V = h ? V2 : V1;
        sV[h][rem / BAS][rem % BAS] = V[(size_t)row * (DDIM * BAS) + rem];
    }
    __syncthreads();
    const int l = tid >> 6, u = tid & 63;
    const float4* y4 = reinterpret_cast<const float4*>(
        Yeq + (size_t)row * 2048 + l * 1024 + u * BAS);
    float a0 = 0.f, a1 = 0.f, a2 = 0.f;
    #pragma unroll
    for (int q = 0; q < 4; ++q) {
        float4 w = y4[q];
        const float* v0 = sV[l][0] + q * 4;
        const float* v1 = sV[l][1] + q * 4;
        const float* v2 = sV[l][2] + q * 4;
        a0 += w.x * v0[0] + w.y * v0[1] + w.z * v0[2] + w.w * v0[3];
        a1 += w.x * v1[0] + w.y * v1[1] + w.z * v1[2] + w.w * v1[3];
        a2 += w.x * v2[0] + w.y * v2[1] + w.z * v2[2] + w.w * v2[3];
    }
    float* o = out_eq + (size_t)row * (DDIM * 128);
    o[0 * 128 + l * 64 + u] = a0;
    o[1 * 128 + l * 64 + u] = a1;
    o[2 * 128 + l * 64 + u] = a2;
}

// ---------------------------------------------------------------------------
extern "C" void kernel_launch(void* const* d_in, const int* in_sizes, int n_in,
                              void* d_out, int out_size, void* d_ws, size_t ws_size,
                              hipStream_t stream) {
    const float* t1    = (const float*)d_in[0];
    const float* t2    = (const float*)d_in[1];
    const float* u1    = (const float*)d_in[2];
    const float* u2    = (const float*)d_in[3];
    const float* V1    = (const float*)d_in[4];
    const float* V2    = (const float*)d_in[5];
    const float* W_inv = (const float*)d_in[6];
    const float* b_inv = (const float*)d_in[7];
    const float* g_inv = (const float*)d_in[8];
    const float* be_inv= (const float*)d_in[9];
    const float* W_eq  = (const float*)d_in[10];
    const float* b_eq  = (const float*)d_in[11];
    const float* g_eq  = (const float*)d_in[12];
    const float* be_eq = (const float*)d_in[13];
    float* out = (float*)d_out;

    // workspace layout (bytes)
    char* ws = (char*)d_ws;
    __hip_bfloat16* feats = (__hip_bfloat16*)(ws);                       // 134,217,728
    __hip_bfloat16* WT    = (__hip_bfloat16*)(ws + 134217728);           //  41,943,040
    float*          Yeq   = (float*)(ws + 176160768);                    //  67,108,864
    float*          cb    = (float*)(ws + 243269632);
    float*          cg    = (float*)(ws + 243279872);
    float*          cbe   = (float*)(ws + 243290112);

    float* out_inv = out;                                  // [8192][512]
    float* out_eq  = out + (size_t)BROWS * NINV;           // [8192][3][128]

    hipLaunchKernelGGL(feats_kernel, dim3(BROWS), dim3(256), 0, stream,
                       t1, t2, u1, u2, feats);
    hipLaunchKernelGGL(wt_kernel, dim3(NTOT / 32, KF / 32), dim3(256), 0, stream,
                       W_inv, W_eq, WT);
    hipLaunchKernelGGL(params_kernel, dim3((NTOT + 255) / 256), dim3(256), 0, stream,
                       b_inv, g_inv, be_inv, b_eq, g_eq, be_eq, cb, cg, cbe);
    hipLaunchKernelGGL(gemm_kernel, dim3((NTOT / BN) * (BROWS / BM)), dim3(128), 0, stream,
                       feats, WT, cb, cg, cbe, out_inv, Yeq);
    hipLaunchKernelGGL(eqcomb_kernel, dim3(BROWS), dim3(128), 0, stream,
                       Yeq, V1, V2, out_eq);
}

// Round 6
// 706.793 us; speedup vs baseline: 1.9212x; 1.0397x over previous
//
#include <hip/hip_runtime.h>
#include <hip/hip_bf16.h>

// Problem constants
#define BROWS 8192      // B*N = 8*1024
#define DDIM 3
#define CDIM 64
#define KF 8192         // F = 2*C*C
#define NINV 512
#define NEQ 1024        // per head
#define NTOT 2560       // 512 + 1024 + 1024
#define BAS 16
#define UEQ 64

// Packed-tile layout (shared by feats/wt producers and the GEMM consumer):
//   tile (mb, kt) = 128 rows x 32 k bf16 = 8 KB, stored contiguously at
//   byte offset ((mb*256 + kt) << 13).  Within a tile, element (rloc, kk):
//     logical chunk lc = (kk>>3)&3, phys = (lc + (rloc>>1)) & 3  (bank swizzle)
//     byte = rloc*64 + phys*16 + (kk&7)*2
// This is exactly the LDS image the GEMM reads, so staging is a linear memcpy.

typedef float f32x4 __attribute__((ext_vector_type(4)));
typedef __bf16 bf16x8_t __attribute__((ext_vector_type(8)));
typedef __bf16 bf16x4_t __attribute__((ext_vector_type(4)));

__device__ __forceinline__ void async_copy16(const void* g, void* l) {
    __builtin_amdgcn_global_load_lds(
        (__attribute__((address_space(1))) void*)(g),
        (__attribute__((address_space(3))) void*)(l), 16, 0, 0);
}

// ---------------------------------------------------------------------------
// Kernel 1: per-row l2norm + Gram blocks -> packed feats tiles
// ---------------------------------------------------------------------------
__global__ __launch_bounds__(256) void feats_kernel(
    const float* __restrict__ t1, const float* __restrict__ t2,
    const float* __restrict__ u1, const float* __restrict__ u2,
    __hip_bfloat16* __restrict__ feats)   // packed [64][256][8KB]
{
    const int row = blockIdx.x;
    const int tid = threadIdx.x;
    __shared__ float sT[2 * DDIM * CDIM];   // [head][d][c]
    __shared__ float sU[2 * DDIM * CDIM];   // scaled u

    const size_t base = (size_t)row * (DDIM * CDIM);
    if (tid < 192) {
        sT[tid]       = t1[base + tid];
        sT[192 + tid] = t2[base + tid];
        sU[tid]       = u1[base + tid];
        sU[192 + tid] = u2[base + tid];
    }
    __syncthreads();
    if (tid < 128) {
        const int h = tid >> 6, c = tid & 63;
        float* U = sU + h * 192;
        float sq = U[c] * U[c] + U[64 + c] * U[64 + c] + U[128 + c] * U[128 + c];
        float s = 1.0f / sqrtf(fmaxf(sq, 0.01f));
        U[c] *= s; U[64 + c] *= s; U[128 + c] *= s;
    }
    __syncthreads();
    // thread -> (h, i, j-half); covers one 32-k tile span = one packed 64B line
    const int h  = tid >> 7;            // 0..1
    const int i  = (tid >> 1) & 63;     // 0..63
    const int jh = (tid & 1) * 32;      // 0 or 32
    const float* T = sT + h * 192;
    const float* U = sU + h * 192;
    const float ti0 = T[i], ti1 = T[64 + i], ti2 = T[128 + i];

    const int kbase = h * 4096 + i * 64 + jh;   // 32-aligned global k
    const int kt    = kbase >> 5;
    const int mb    = row >> 7, rloc = row & 127;
    char* line = (char*)feats + (((size_t)(mb * 256 + kt)) << 13) + rloc * 64;

    #pragma unroll
    for (int g = 0; g < 4; ++g) {                 // logical chunk
        const int phys = (g + (rloc >> 1)) & 3;
        #pragma unroll
        for (int half = 0; half < 2; ++half) {
            const int j = jh + g * 8 + half * 4;  // within-head col, mult of 4
            const float4 u0 = *reinterpret_cast<const float4*>(U + j);
            const float4 u1 = *reinterpret_cast<const float4*>(U + 64 + j);
            const float4 u2 = *reinterpret_cast<const float4*>(U + 128 + j);
            bf16x4_t v;
            v[0] = (__bf16)(ti0 * u0.x + ti1 * u1.x + ti2 * u2.x);
            v[1] = (__bf16)(ti0 * u0.y + ti1 * u1.y + ti2 * u2.y);
            v[2] = (__bf16)(ti0 * u0.z + ti1 * u1.z + ti2 * u2.z);
            v[3] = (__bf16)(ti0 * u0.w + ti1 * u1.w + ti2 * u2.w);
            *reinterpret_cast<bf16x4_t*>(line + phys * 16 + half * 8) = v;
        }
    }
}

// ---------------------------------------------------------------------------
// Kernel 2: transpose+convert W (K x N fp32, three sources) -> packed WT tiles
// ---------------------------------------------------------------------------
__global__ __launch_bounds__(256) void wt_kernel(
    const float* __restrict__ W_inv, const float* __restrict__ W_eq,
    __hip_bfloat16* __restrict__ WT)   // packed [20][256][8KB]
{
    __shared__ float tile[32][33];
    const int tid = threadIdx.x;
    const int tx = tid & 31;          // n within tile (load)
    const int ty = tid >> 5;          // 0..7
    const int n0 = blockIdx.x * 32;   // output column block (0..2559)
    const int k0 = blockIdx.y * 32;   // K block (0..8191)

    const float* src; int ldn, nl0;
    if (n0 < NINV)            { src = W_inv;                       ldn = NINV; nl0 = n0; }
    else if (n0 < NINV + NEQ) { src = W_eq;                        ldn = NEQ;  nl0 = n0 - NINV; }
    else                      { src = W_eq + (size_t)KF * NEQ;     ldn = NEQ;  nl0 = n0 - NINV - NEQ; }

    #pragma unroll
    for (int i = 0; i < 4; ++i) {
        int kl = ty + i * 8;
        tile[kl][tx] = src[(size_t)(k0 + kl) * ldn + nl0 + tx];
    }
    __syncthreads();
    // store phase: each thread packs 4 consecutive k for one n (8 B store)
    const int n_l = tid >> 3;         // 0..31
    const int k4  = (tid & 7) * 4;    // 0..28
    bf16x4_t v;
    #pragma unroll
    for (int q = 0; q < 4; ++q) v[q] = (__bf16)tile[k4 + q][n_l];

    const int n    = n0 + n_l;
    const int nb   = n >> 7, rloc = n & 127;
    const int kt   = k0 >> 5;
    const int lc   = (k4 >> 3) & 3, e = k4 & 7;
    const int phys = (lc + (rloc >> 1)) & 3;
    char* dst = (char*)WT + (((size_t)(nb * 256 + kt)) << 13)
              + rloc * 64 + phys * 16 + e * 2;
    *reinterpret_cast<bf16x4_t*>(dst) = v;
}

// ---------------------------------------------------------------------------
// Kernel 3: concat BN params into [NTOT] arrays
// ---------------------------------------------------------------------------
__global__ __launch_bounds__(256) void params_kernel(
    const float* __restrict__ b_inv, const float* __restrict__ g_inv, const float* __restrict__ be_inv,
    const float* __restrict__ b_eq,  const float* __restrict__ g_eq,  const float* __restrict__ be_eq,
    float* __restrict__ cb, float* __restrict__ cg, float* __restrict__ cbe)
{
    int n = blockIdx.x * 256 + threadIdx.x;
    if (n >= NTOT) return;
    float b, g, be;
    if (n < NINV) { b = b_inv[n]; g = g_inv[n]; be = be_inv[n]; }
    else {
        int h = (n - NINV) / NEQ, nl = (n - NINV) % NEQ;
        b = b_eq[h * NEQ + nl]; g = g_eq[h * NEQ + nl]; be = be_eq[h * NEQ + nl];
    }
    cb[n] = b; cg[n] = g; cbe[n] = be;
}

// ---------------------------------------------------------------------------
// Kernel 4: bf16 MFMA GEMM on packed tiles. 128 threads = 2 waves, wave tile
// 64x128, 32 MFMA per barrier-pair. Staging = linear 8KB-tile memcpy streams.
// ---------------------------------------------------------------------------
#define BM 128
#define BN 128
#define BK 32

struct GemmCtx {
    const char* pA;      // packed A tile stream for this mb
    const char* pB;      // packed B tile stream for this nb
    __hip_bfloat16* As[2];
    __hip_bfloat16* Bs[2];
    int soff;    // byte offset of this lane's first 1KB segment
    int chnk;    // element offset of 16B chunk for ds_read
    int wm, lane;
};

__device__ __forceinline__ void issue8(const GemmCtx& c, int buf, size_t tileoff) {
    #pragma unroll
    for (int j = 0; j < 4; ++j)
        async_copy16(c.pA + tileoff + c.soff + j * 1024,
                     (char*)c.As[buf] + c.soff + j * 1024);
    #pragma unroll
    for (int j = 0; j < 4; ++j)
        async_copy16(c.pB + tileoff + c.soff + j * 1024,
                     (char*)c.Bs[buf] + c.soff + j * 1024);
}

__device__ __forceinline__ void compute32(const GemmCtx& c, int buf, f32x4 (&acc)[4][8]) {
    const int l15 = c.lane & 15;
    bf16x8_t a[4], b[8];
    #pragma unroll
    for (int mt = 0; mt < 4; ++mt)
        a[mt] = *reinterpret_cast<const bf16x8_t*>(
            &c.As[buf][(c.wm + mt * 16 + l15) * BK + c.chnk]);
    #pragma unroll
    for (int nt = 0; nt < 8; ++nt)
        b[nt] = *reinterpret_cast<const bf16x8_t*>(
            &c.Bs[buf][(nt * 16 + l15) * BK + c.chnk]);
    #pragma unroll
    for (int mt = 0; mt < 4; ++mt)
        #pragma unroll
        for (int nt = 0; nt < 8; ++nt)
            acc[mt][nt] = __builtin_amdgcn_mfma_f32_16x16x32_bf16(
                a[mt], b[nt], acc[mt][nt], 0, 0, 0);
}

__global__ __launch_bounds__(128, 2) void gemm_kernel(
    const __hip_bfloat16* __restrict__ A,   // packed [64][256][8KB]
    const __hip_bfloat16* __restrict__ BT,  // packed [20][256][8KB]
    const float* __restrict__ cb, const float* __restrict__ cg, const float* __restrict__ cbe,
    float* __restrict__ out_inv,            // d_out: [BROWS][NINV]
    float* __restrict__ Yeq)                // ws:    [BROWS][2048]
{
    __shared__ alignas(16) __hip_bfloat16 AsBuf[2][BM * BK];  // 2 x 8 KB
    __shared__ alignas(16) __hip_bfloat16 BsBuf[2][BN * BK];  // 2 x 8 KB

    const int tid  = threadIdx.x;
    const int wave = tid >> 6;
    const int lane = tid & 63;

    // XCD-aware decode: xcd = b%8 owns 8 contiguous m-stripes, n fastest.
    const int b    = blockIdx.x;
    const int xcd  = b & 7;
    const int slot = b >> 3;            // 0..159
    const int nb   = slot % 20;
    const int mb   = xcd * 8 + slot / 20;
    const int n0   = nb * BN;
    const int m0   = mb * BM;

    GemmCtx c;
    c.wm   = wave * 64;
    c.lane = lane;
    c.As[0] = &AsBuf[0][0]; c.As[1] = &AsBuf[1][0];
    c.Bs[0] = &BsBuf[0][0]; c.Bs[1] = &BsBuf[1][0];
    c.pA = (const char*)A  + ((size_t)mb << 21);   // mb * 2 MB
    c.pB = (const char*)BT + ((size_t)nb << 21);   // nb * 2 MB
    c.soff = wave * 4096 + lane * 16;
    c.chnk = (((lane >> 4) + ((lane & 15) >> 1)) & 3) * 8;

    f32x4 acc[4][8] = {};

    issue8(c, 0, 0);   // prologue: tile 0 -> buf 0

    for (int kt = 0; kt < 256; kt += 2) {
        // phase A: compute buf0 @ kt, prefetch buf1 @ kt+1 (always valid)
        issue8(c, 1, ((size_t)(kt + 1)) << 13);
        asm volatile("s_waitcnt vmcnt(8)" ::: "memory");
        __builtin_amdgcn_s_barrier();
        asm volatile("" ::: "memory");
        compute32(c, 0, acc);
        asm volatile("" ::: "memory");
        __builtin_amdgcn_s_barrier();

        // phase B: compute buf1 @ kt+1, prefetch buf0 @ kt+2
        if (kt + 2 < 256) {
            issue8(c, 0, ((size_t)(kt + 2)) << 13);
            asm volatile("s_waitcnt vmcnt(8)" ::: "memory");
        } else {
            asm volatile("s_waitcnt vmcnt(0)" ::: "memory");
        }
        __builtin_amdgcn_s_barrier();
        asm volatile("" ::: "memory");
        compute32(c, 1, acc);
        asm volatile("" ::: "memory");
        __builtin_amdgcn_s_barrier();
    }

    // epilogue: y = relu(g * (acc + b) / sqrt(1.001) + be)
    const float RSQ = 0.9995003746877732f;
    #pragma unroll
    for (int nt = 0; nt < 8; ++nt) {
        const int gn = n0 + nt * 16 + (lane & 15);
        const float bbp = cb[gn];
        const float gg  = cg[gn] * RSQ;
        const float bep = cbe[gn];
        #pragma unroll
        for (int mt = 0; mt < 4; ++mt) {
            const int gmb = m0 + c.wm + mt * 16 + ((lane >> 4) << 2);
            #pragma unroll
            for (int rr = 0; rr < 4; ++rr) {
                float y = fmaxf(gg * (acc[mt][nt][rr] + bbp) + bep, 0.0f);
                const size_t gm = gmb + rr;
                if (n0 < NINV) out_inv[gm * NINV + gn] = y;
                else           Yeq[gm * 2048 + (gn - NINV)] = y;
            }
        }
    }
}

// ---------------------------------------------------------------------------
// Kernel 5: basis recombine
// ---------------------------------------------------------------------------
__global__ __launch_bounds__(128) void eqcomb_kernel(
    const float* __restrict__ Yeq,   // [BROWS][2048]
    const float* __restrict__ V1, const float* __restrict__ V2,
    float* __restrict__ out_eq)      // [BROWS][3][128]
{
    const int row = blockIdx.x;
    const int tid = threadIdx.x;     // 128
    __shared__ float sV[2][DDIM][BAS];
    if (tid < 96) {
        const int h = tid / 48, rem = tid % 48;
        const float* V = h ? V2 : V1;
        sV[h][rem / BAS][rem % BAS] = V[(size_t)row * (DDIM * BAS) + rem];
    }
    __syncthreads();
    const int l = tid >> 6, u = tid & 63;
    const float4* y4 = reinterpret_cast<const float4*>(
        Yeq + (size_t)row * 2048 + l * 1024 + u * BAS);
    float a0 = 0.f, a1 = 0.f, a2 = 0.f;
    #pragma unroll
    for (int q = 0; q < 4; ++q) {
        float4 w = y4[q];
        const float* v0 = sV[l][0] + q * 4;
        const float* v1 = sV[l][1] + q * 4;
        const float* v2 = sV[l][2] + q * 4;
        a0 += w.x * v0[0] + w.y * v0[1] + w.z * v0[2] + w.w * v0[3];
        a1 += w.x * v1[0] + w.y * v1[1] + w.z * v1[2] + w.w * v1[3];
        a2 += w.x * v2[0] + w.y * v2[1] + w.z * v2[2] + w.w * v2[3];
    }
    float* o = out_eq + (size_t)row * (DDIM * 128);
    o[0 * 128 + l * 64 + u] = a0;
    o[1 * 128 + l * 64 + u] = a1;
    o[2 * 128 + l * 64 + u] = a2;
}

// ---------------------------------------------------------------------------
extern "C" void kernel_launch(void* const* d_in, const int* in_sizes, int n_in,
                              void* d_out, int out_size, void* d_ws, size_t ws_size,
                              hipStream_t stream) {
    const float* t1    = (const float*)d_in[0];
    const float* t2    = (const float*)d_in[1];
    const float* u1    = (const float*)d_in[2];
    const float* u2    = (const float*)d_in[3];
    const float* V1    = (const float*)d_in[4];
    const float* V2    = (const float*)d_in[5];
    const float* W_inv = (const float*)d_in[6];
    const float* b_inv = (const float*)d_in[7];
    const float* g_inv = (const float*)d_in[8];
    const float* be_inv= (const float*)d_in[9];
    const float* W_eq  = (const float*)d_in[10];
    const float* b_eq  = (const float*)d_in[11];
    const float* g_eq  = (const float*)d_in[12];
    const float* be_eq = (const float*)d_in[13];
    float* out = (float*)d_out;

    // workspace layout (bytes)
    char* ws = (char*)d_ws;
    __hip_bfloat16* feats = (__hip_bfloat16*)(ws);                       // 134,217,728 (packed)
    __hip_bfloat16* WT    = (__hip_bfloat16*)(ws + 134217728);           //  41,943,040 (packed)
    float*          Yeq   = (float*)(ws + 176160768);                    //  67,108,864
    float*          cb    = (float*)(ws + 243269632);
    float*          cg    = (float*)(ws + 243279872);
    float*          cbe   = (float*)(ws + 243290112);

    float* out_inv = out;                                  // [8192][512]
    float* out_eq  = out + (size_t)BROWS * NINV;           // [8192][3][128]

    hipLaunchKernelGGL(feats_kernel, dim3(BROWS), dim3(256), 0, stream,
                       t1, t2, u1, u2, feats);
    hipLaunchKernelGGL(wt_kernel, dim3(NTOT / 32, KF / 32), dim3(256), 0, stream,
                       W_inv, W_eq, WT);
    hipLaunchKernelGGL(params_kernel, dim3((NTOT + 255) / 256), dim3(256), 0, stream,
                       b_inv, g_inv, be_inv, b_eq, g_eq, be_eq, cb, cg, cbe);
    hipLaunchKernelGGL(gemm_kernel, dim3((NTOT / BN) * (BROWS / BM)), dim3(128), 0, stream,
                       feats, WT, cb, cg, cbe, out_inv, Yeq);
    hipLaunchKernelGGL(eqcomb_kernel, dim3(BROWS), dim3(128), 0, stream,
                       Yeq, V1, V2, out_eq);
}

// Round 7
// 625.086 us; speedup vs baseline: 2.1724x; 1.1307x over previous
//
#include <hip/hip_runtime.h>
#include <hip/hip_bf16.h>

// Problem constants
#define BROWS 8192      // B*N = 8*1024
#define DDIM 3
#define CDIM 64
#define KF 8192         // F = 2*C*C
#define NINV 512
#define NEQ 1024        // per head
#define NTOT 2560       // 512 + 1024 + 1024
#define BAS 16
#define UEQ 64

// Packed-tile layout v2 (producers and GEMM agree):
//   tile (sb, kt) = 256 rows x 32 k bf16 = 16 KB, at byte ((sb*256 + kt) << 14).
//   Within a tile, element (rloc, kk):
//     logical chunk lc = (kk>>3)&3, phys = (lc + (rloc>>1)) & 3  (bank swizzle)
//     byte = rloc*64 + phys*16 + (kk&7)*2
// Staging is a linear 16KB memcpy per tile.

typedef float f32x4 __attribute__((ext_vector_type(4)));
typedef __bf16 bf16x8_t __attribute__((ext_vector_type(8)));
typedef __bf16 bf16x4_t __attribute__((ext_vector_type(4)));

__device__ __forceinline__ void async_copy16(const void* g, void* l) {
    __builtin_amdgcn_global_load_lds(
        (__attribute__((address_space(1))) void*)(g),
        (__attribute__((address_space(3))) void*)(l), 16, 0, 0);
}

// ---------------------------------------------------------------------------
// Kernel 1: per-row l2norm + Gram blocks -> packed feats tiles [32][256][16KB]
// ---------------------------------------------------------------------------
__global__ __launch_bounds__(256) void feats_kernel(
    const float* __restrict__ t1, const float* __restrict__ t2,
    const float* __restrict__ u1, const float* __restrict__ u2,
    __hip_bfloat16* __restrict__ feats)
{
    const int row = blockIdx.x;
    const int tid = threadIdx.x;
    __shared__ float sT[2 * DDIM * CDIM];   // [head][d][c]
    __shared__ float sU[2 * DDIM * CDIM];   // scaled u

    const size_t base = (size_t)row * (DDIM * CDIM);
    if (tid < 192) {
        sT[tid]       = t1[base + tid];
        sT[192 + tid] = t2[base + tid];
        sU[tid]       = u1[base + tid];
        sU[192 + tid] = u2[base + tid];
    }
    __syncthreads();
    if (tid < 128) {
        const int h = tid >> 6, c = tid & 63;
        float* U = sU + h * 192;
        float sq = U[c] * U[c] + U[64 + c] * U[64 + c] + U[128 + c] * U[128 + c];
        float s = 1.0f / sqrtf(fmaxf(sq, 0.01f));
        U[c] *= s; U[64 + c] *= s; U[128 + c] *= s;
    }
    __syncthreads();
    // thread -> (h, i, j-half); covers one 32-k tile span = one packed 64B line
    const int h  = tid >> 7;            // 0..1
    const int i  = (tid >> 1) & 63;     // 0..63
    const int jh = (tid & 1) * 32;      // 0 or 32
    const float* T = sT + h * 192;
    const float* U = sU + h * 192;
    const float ti0 = T[i], ti1 = T[64 + i], ti2 = T[128 + i];

    const int kbase = h * 4096 + i * 64 + jh;   // 32-aligned global k
    const int kt    = kbase >> 5;
    const int mb    = row >> 8, rloc = row & 255;
    char* line = (char*)feats + (((size_t)(mb * 256 + kt)) << 14) + rloc * 64;

    #pragma unroll
    for (int g = 0; g < 4; ++g) {                 // logical chunk
        const int phys = (g + (rloc >> 1)) & 3;
        #pragma unroll
        for (int half = 0; half < 2; ++half) {
            const int j = jh + g * 8 + half * 4;  // within-head col, mult of 4
            const float4 u0 = *reinterpret_cast<const float4*>(U + j);
            const float4 u1 = *reinterpret_cast<const float4*>(U + 64 + j);
            const float4 u2 = *reinterpret_cast<const float4*>(U + 128 + j);
            bf16x4_t v;
            v[0] = (__bf16)(ti0 * u0.x + ti1 * u1.x + ti2 * u2.x);
            v[1] = (__bf16)(ti0 * u0.y + ti1 * u1.y + ti2 * u2.y);
            v[2] = (__bf16)(ti0 * u0.z + ti1 * u1.z + ti2 * u2.z);
            v[3] = (__bf16)(ti0 * u0.w + ti1 * u1.w + ti2 * u2.w);
            *reinterpret_cast<bf16x4_t*>(line + phys * 16 + half * 8) = v;
        }
    }
}

// ---------------------------------------------------------------------------
// Kernel 2: transpose+convert W (K x N fp32) -> packed WT tiles [10][256][16KB]
// ---------------------------------------------------------------------------
__global__ __launch_bounds__(256) void wt_kernel(
    const float* __restrict__ W_inv, const float* __restrict__ W_eq,
    __hip_bfloat16* __restrict__ WT)
{
    __shared__ float tile[32][33];
    const int tid = threadIdx.x;
    const int tx = tid & 31;          // n within tile (load)
    const int ty = tid >> 5;          // 0..7
    const int n0 = blockIdx.x * 32;   // output column block (0..2559)
    const int k0 = blockIdx.y * 32;   // K block (0..8191)

    const float* src; int ldn, nl0;
    if (n0 < NINV)            { src = W_inv;                       ldn = NINV; nl0 = n0; }
    else if (n0 < NINV + NEQ) { src = W_eq;                        ldn = NEQ;  nl0 = n0 - NINV; }
    else                      { src = W_eq + (size_t)KF * NEQ;     ldn = NEQ;  nl0 = n0 - NINV - NEQ; }

    #pragma unroll
    for (int i = 0; i < 4; ++i) {
        int kl = ty + i * 8;
        tile[kl][tx] = src[(size_t)(k0 + kl) * ldn + nl0 + tx];
    }
    __syncthreads();
    // store phase: each thread packs 4 consecutive k for one n (8 B store)
    const int n_l = tid >> 3;         // 0..31
    const int k4  = (tid & 7) * 4;    // 0..28
    bf16x4_t v;
    #pragma unroll
    for (int q = 0; q < 4; ++q) v[q] = (__bf16)tile[k4 + q][n_l];

    const int n    = n0 + n_l;
    const int nb   = n >> 8, rloc = n & 255;
    const int kt   = k0 >> 5;
    const int lc   = (k4 >> 3) & 3, e = k4 & 7;
    const int phys = (lc + (rloc >> 1)) & 3;
    char* dst = (char*)WT + (((size_t)(nb * 256 + kt)) << 14)
              + rloc * 64 + phys * 16 + e * 2;
    *reinterpret_cast<bf16x4_t*>(dst) = v;
}

// ---------------------------------------------------------------------------
// Kernel 3: bf16 MFMA GEMM on packed 256-tiles. 512 threads = 8 waves
// (4m x 2n), wave tile 64x128, BM=BN=256 -> staged volume 2.62 GB (half of
// 128^2). BN params fused into epilogue.
// ---------------------------------------------------------------------------
#define BM 256
#define BN 256
#define BK 32

struct GemmCtx {
    const char* pA;      // packed A tile stream for this mb
    const char* pB;      // packed B tile stream for this nb
    __hip_bfloat16* As[2];
    __hip_bfloat16* Bs[2];
    int soff;    // byte offset of this thread's 16B staging slot
    int chnk;    // element offset of 16B chunk for ds_read
    int wm, wn, lane;
};

__device__ __forceinline__ void issue4(const GemmCtx& c, int buf, size_t toff) {
    #pragma unroll
    for (int j = 0; j < 2; ++j)
        async_copy16(c.pA + toff + c.soff + j * 8192,
                     (char*)c.As[buf] + c.soff + j * 8192);
    #pragma unroll
    for (int j = 0; j < 2; ++j)
        async_copy16(c.pB + toff + c.soff + j * 8192,
                     (char*)c.Bs[buf] + c.soff + j * 8192);
}

__device__ __forceinline__ void compute32(const GemmCtx& c, int buf, f32x4 (&acc)[4][8]) {
    const int l15 = c.lane & 15;
    bf16x8_t a[4], b[8];
    #pragma unroll
    for (int mt = 0; mt < 4; ++mt)
        a[mt] = *reinterpret_cast<const bf16x8_t*>(
            &c.As[buf][(c.wm + mt * 16 + l15) * BK + c.chnk]);
    #pragma unroll
    for (int nt = 0; nt < 8; ++nt)
        b[nt] = *reinterpret_cast<const bf16x8_t*>(
            &c.Bs[buf][(c.wn + nt * 16 + l15) * BK + c.chnk]);
    #pragma unroll
    for (int mt = 0; mt < 4; ++mt)
        #pragma unroll
        for (int nt = 0; nt < 8; ++nt)
            acc[mt][nt] = __builtin_amdgcn_mfma_f32_16x16x32_bf16(
                a[mt], b[nt], acc[mt][nt], 0, 0, 0);
}

__global__ __launch_bounds__(512, 2) void gemm_kernel(
    const __hip_bfloat16* __restrict__ A,   // packed [32][256][16KB]
    const __hip_bfloat16* __restrict__ BT,  // packed [10][256][16KB]
    const float* __restrict__ b_inv, const float* __restrict__ g_inv,
    const float* __restrict__ be_inv,
    const float* __restrict__ b_eq,  const float* __restrict__ g_eq,
    const float* __restrict__ be_eq,
    float* __restrict__ out_inv,            // d_out: [BROWS][NINV]
    float* __restrict__ Yeq)                // ws:    [BROWS][2048]
{
    __shared__ alignas(16) __hip_bfloat16 AsBuf[2][BM * BK];  // 2 x 16 KB
    __shared__ alignas(16) __hip_bfloat16 BsBuf[2][BN * BK];  // 2 x 16 KB

    const int tid  = threadIdx.x;
    const int wave = tid >> 6;
    const int lane = tid & 63;

    // XCD-aware decode: 320 blocks; xcd = b%8 owns 4 m-stripes, n fastest.
    const int b    = blockIdx.x;
    const int xcd  = b & 7;
    const int slot = b >> 3;            // 0..39
    const int nb   = slot % 10;
    const int mb   = xcd * 4 + slot / 10;
    const int n0   = nb * BN;
    const int m0   = mb * BM;

    GemmCtx c;
    c.wm   = (wave & 3) * 64;
    c.wn   = (wave >> 2) * 128;
    c.lane = lane;
    c.As[0] = &AsBuf[0][0]; c.As[1] = &AsBuf[1][0];
    c.Bs[0] = &BsBuf[0][0]; c.Bs[1] = &BsBuf[1][0];
    c.pA = (const char*)A  + ((size_t)mb << 22);   // mb * 4 MB
    c.pB = (const char*)BT + ((size_t)nb << 22);   // nb * 4 MB
    c.soff = tid * 16;
    c.chnk = (((lane >> 4) + ((lane & 15) >> 1)) & 3) * 8;

    f32x4 acc[4][8] = {};

    issue4(c, 0, 0);   // prologue: tile 0 -> buf 0

    for (int kt = 0; kt < 256; kt += 2) {
        // phase A: compute buf0 @ kt, prefetch buf1 @ kt+1 (always valid)
        issue4(c, 1, ((size_t)(kt + 1)) << 14);
        asm volatile("s_waitcnt vmcnt(4)" ::: "memory");
        __builtin_amdgcn_s_barrier();
        asm volatile("" ::: "memory");
        compute32(c, 0, acc);
        asm volatile("" ::: "memory");
        __builtin_amdgcn_s_barrier();

        // phase B: compute buf1 @ kt+1, prefetch buf0 @ kt+2
        if (kt + 2 < 256) {
            issue4(c, 0, ((size_t)(kt + 2)) << 14);
            asm volatile("s_waitcnt vmcnt(4)" ::: "memory");
        } else {
            asm volatile("s_waitcnt vmcnt(0)" ::: "memory");
        }
        __builtin_amdgcn_s_barrier();
        asm volatile("" ::: "memory");
        compute32(c, 1, acc);
        asm volatile("" ::: "memory");
        __builtin_amdgcn_s_barrier();
    }

    // epilogue: y = relu(g * (acc + b) / sqrt(1.001) + be), params fused
    const float RSQ = 0.9995003746877732f;
    #pragma unroll
    for (int nt = 0; nt < 8; ++nt) {
        const int gn = n0 + c.wn + nt * 16 + (lane & 15);
        float bbp, gg, bep;
        if (gn < NINV) {
            bbp = b_inv[gn]; gg = g_inv[gn]; bep = be_inv[gn];
        } else {
            const int e = gn - NINV, hh = e >> 10, nl = e & 1023;
            bbp = b_eq[hh * NEQ + nl]; gg = g_eq[hh * NEQ + nl]; bep = be_eq[hh * NEQ + nl];
        }
        gg *= RSQ;
        #pragma unroll
        for (int mt = 0; mt < 4; ++mt) {
            const int gmb = m0 + c.wm + mt * 16 + ((lane >> 4) << 2);
            #pragma unroll
            for (int rr = 0; rr < 4; ++rr) {
                float y = fmaxf(gg * (acc[mt][nt][rr] + bbp) + bep, 0.0f);
                const size_t gm = gmb + rr;
                if (gn < NINV) out_inv[gm * NINV + gn] = y;
                else           Yeq[gm * 2048 + (gn - NINV)] = y;
            }
        }
    }
}

// ---------------------------------------------------------------------------
// Kernel 4: basis recombine
// ---------------------------------------------------------------------------
__global__ __launch_bounds__(128) void eqcomb_kernel(
    const float* __restrict__ Yeq,   // [BROWS][2048]
    const float* __restrict__ V1, const float* __restrict__ V2,
    float* __restrict__ out_eq)      // [BROWS][3][128]
{
    const int row = blockIdx.x;
    const int tid = threadIdx.x;     // 128
    __shared__ float sV[2][DDIM][BAS];
    if (tid < 96) {
        const int h = tid / 48, rem = tid % 48;
        const float* V = h ? V2 : V1;
        sV[h][rem / BAS][rem % BAS] = V[(size_t)row * (DDIM * BAS) + rem];
    }
    __syncthreads();
    const int l = tid >> 6, u = tid & 63;
    const float4* y4 = reinterpret_cast<const float4*>(
        Yeq + (size_t)row * 2048 + l * 1024 + u * BAS);
    float a0 = 0.f, a1 = 0.f, a2 = 0.f;
    #pragma unroll
    for (int q = 0; q < 4; ++q) {
        float4 w = y4[q];
        const float* v0 = sV[l][0] + q * 4;
        const float* v1 = sV[l][1] + q * 4;
        const float* v2 = sV[l][2] + q * 4;
        a0 += w.x * v0[0] + w.y * v0[1] + w.z * v0[2] + w.w * v0[3];
        a1 += w.x * v1[0] + w.y * v1[1] + w.z * v1[2] + w.w * v1[3];
        a2 += w.x * v2[0] + w.y * v2[1] + w.z * v2[2] + w.w * v2[3];
    }
    float* o = out_eq + (size_t)row * (DDIM * 128);
    o[0 * 128 + l * 64 + u] = a0;
    o[1 * 128 + l * 64 + u] = a1;
    o[2 * 128 + l * 64 + u] = a2;
}

// ---------------------------------------------------------------------------
extern "C" void kernel_launch(void* const* d_in, const int* in_sizes, int n_in,
                              void* d_out, int out_size, void* d_ws, size_t ws_size,
                              hipStream_t stream) {
    const float* t1    = (const float*)d_in[0];
    const float* t2    = (const float*)d_in[1];
    const float* u1    = (const float*)d_in[2];
    const float* u2    = (const float*)d_in[3];
    const float* V1    = (const float*)d_in[4];
    const float* V2    = (const float*)d_in[5];
    const float* W_inv = (const float*)d_in[6];
    const float* b_inv = (const float*)d_in[7];
    const float* g_inv = (const float*)d_in[8];
    const float* be_inv= (const float*)d_in[9];
    const float* W_eq  = (const float*)d_in[10];
    const float* b_eq  = (const float*)d_in[11];
    const float* g_eq  = (const float*)d_in[12];
    const float* be_eq = (const float*)d_in[13];
    float* out = (float*)d_out;

    // workspace layout (bytes)
    char* ws = (char*)d_ws;
    __hip_bfloat16* feats = (__hip_bfloat16*)(ws);                       // 134,217,728 (packed)
    __hip_bfloat16* WT    = (__hip_bfloat16*)(ws + 134217728);           //  41,943,040 (packed)
    float*          Yeq   = (float*)(ws + 176160768);                    //  67,108,864

    float* out_inv = out;                                  // [8192][512]
    float* out_eq  = out + (size_t)BROWS * NINV;           // [8192][3][128]

    hipLaunchKernelGGL(feats_kernel, dim3(BROWS), dim3(256), 0, stream,
                       t1, t2, u1, u2, feats);
    hipLaunchKernelGGL(wt_kernel, dim3(NTOT / 32, KF / 32), dim3(256), 0, stream,
                       W_inv, W_eq, WT);
    hipLaunchKernelGGL(gemm_kernel, dim3((NTOT / BN) * (BROWS / BM)), dim3(512), 0, stream,
                       feats, WT, b_inv, g_inv, be_inv, b_eq, g_eq, be_eq,
                       out_inv, Yeq);
    hipLaunchKernelGGL(eqcomb_kernel, dim3(BROWS), dim3(128), 0, stream,
                       Yeq, V1, V2, out_eq);
}

// Round 8
// 597.168 us; speedup vs baseline: 2.2739x; 1.0468x over previous
//
#include <hip/hip_runtime.h>
#include <hip/hip_bf16.h>

// Problem constants
#define BROWS 8192      // B*N = 8*1024
#define DDIM 3
#define CDIM 64
#define KF 8192         // F = 2*C*C
#define NINV 512
#define NEQ 1024        // per head
#define NTOT 2560       // 512 + 1024 + 1024
#define BAS 16
#define UEQ 64

// Packed-tile layouts (producers and GEMM agree):
//  A: tile (mb, kt) = 256 rows x 32 k bf16 = 16 KB at byte ((mb*256+kt) << 14)
//  B: tile (nb, kt) = 320 rows x 32 k bf16 = 20 KB at byte ((nb*256+kt) * 20480)
//  Within a tile, element (rloc, kk):
//    logical chunk lc = (kk>>3)&3, phys = (lc + (rloc>>1)) & 3  (bank swizzle)
//    byte = rloc*64 + phys*16 + (kk&7)*2
// Staging is a linear memcpy per tile.

typedef float f32x4 __attribute__((ext_vector_type(4)));
typedef __bf16 bf16x8_t __attribute__((ext_vector_type(8)));
typedef __bf16 bf16x4_t __attribute__((ext_vector_type(4)));

__device__ __forceinline__ void async_copy16(const void* g, void* l) {
    __builtin_amdgcn_global_load_lds(
        (__attribute__((address_space(1))) void*)(g),
        (__attribute__((address_space(3))) void*)(l), 16, 0, 0);
}

// ---------------------------------------------------------------------------
// Kernel 1: per-row l2norm + Gram blocks -> packed feats tiles [32][256][16KB]
// ---------------------------------------------------------------------------
__global__ __launch_bounds__(256) void feats_kernel(
    const float* __restrict__ t1, const float* __restrict__ t2,
    const float* __restrict__ u1, const float* __restrict__ u2,
    __hip_bfloat16* __restrict__ feats)
{
    const int row = blockIdx.x;
    const int tid = threadIdx.x;
    __shared__ float sT[2 * DDIM * CDIM];   // [head][d][c]
    __shared__ float sU[2 * DDIM * CDIM];   // scaled u

    const size_t base = (size_t)row * (DDIM * CDIM);
    if (tid < 192) {
        sT[tid]       = t1[base + tid];
        sT[192 + tid] = t2[base + tid];
        sU[tid]       = u1[base + tid];
        sU[192 + tid] = u2[base + tid];
    }
    __syncthreads();
    if (tid < 128) {
        const int h = tid >> 6, c = tid & 63;
        float* U = sU + h * 192;
        float sq = U[c] * U[c] + U[64 + c] * U[64 + c] + U[128 + c] * U[128 + c];
        float s = 1.0f / sqrtf(fmaxf(sq, 0.01f));
        U[c] *= s; U[64 + c] *= s; U[128 + c] *= s;
    }
    __syncthreads();
    // thread -> (h, i, j-half); covers one 32-k tile span = one packed 64B line
    const int h  = tid >> 7;            // 0..1
    const int i  = (tid >> 1) & 63;     // 0..63
    const int jh = (tid & 1) * 32;      // 0 or 32
    const float* T = sT + h * 192;
    const float* U = sU + h * 192;
    const float ti0 = T[i], ti1 = T[64 + i], ti2 = T[128 + i];

    const int kbase = h * 4096 + i * 64 + jh;   // 32-aligned global k
    const int kt    = kbase >> 5;
    const int mb    = row >> 8, rloc = row & 255;
    char* line = (char*)feats + (((size_t)(mb * 256 + kt)) << 14) + rloc * 64;

    #pragma unroll
    for (int g = 0; g < 4; ++g) {                 // logical chunk
        const int phys = (g + (rloc >> 1)) & 3;
        #pragma unroll
        for (int half = 0; half < 2; ++half) {
            const int j = jh + g * 8 + half * 4;  // within-head col, mult of 4
            const float4 u0 = *reinterpret_cast<const float4*>(U + j);
            const float4 u1 = *reinterpret_cast<const float4*>(U + 64 + j);
            const float4 u2 = *reinterpret_cast<const float4*>(U + 128 + j);
            bf16x4_t v;
            v[0] = (__bf16)(ti0 * u0.x + ti1 * u1.x + ti2 * u2.x);
            v[1] = (__bf16)(ti0 * u0.y + ti1 * u1.y + ti2 * u2.y);
            v[2] = (__bf16)(ti0 * u0.z + ti1 * u1.z + ti2 * u2.z);
            v[3] = (__bf16)(ti0 * u0.w + ti1 * u1.w + ti2 * u2.w);
            *reinterpret_cast<bf16x4_t*>(line + phys * 16 + half * 8) = v;
        }
    }
}

// ---------------------------------------------------------------------------
// Kernel 2: transpose+convert W (K x N fp32) -> packed WT tiles [8][256][20KB]
// ---------------------------------------------------------------------------
__global__ __launch_bounds__(256) void wt_kernel(
    const float* __restrict__ W_inv, const float* __restrict__ W_eq,
    __hip_bfloat16* __restrict__ WT)
{
    __shared__ float tile[32][33];
    const int tid = threadIdx.x;
    const int tx = tid & 31;          // n within tile (load)
    const int ty = tid >> 5;          // 0..7
    const int n0 = blockIdx.x * 32;   // output column block (0..2559)
    const int k0 = blockIdx.y * 32;   // K block (0..8191)

    const float* src; int ldn, nl0;
    if (n0 < NINV)            { src = W_inv;                       ldn = NINV; nl0 = n0; }
    else if (n0 < NINV + NEQ) { src = W_eq;                        ldn = NEQ;  nl0 = n0 - NINV; }
    else                      { src = W_eq + (size_t)KF * NEQ;     ldn = NEQ;  nl0 = n0 - NINV - NEQ; }

    #pragma unroll
    for (int i = 0; i < 4; ++i) {
        int kl = ty + i * 8;
        tile[kl][tx] = src[(size_t)(k0 + kl) * ldn + nl0 + tx];
    }
    __syncthreads();
    // store phase: each thread packs 4 consecutive k for one n (8 B store)
    const int n_l = tid >> 3;         // 0..31
    const int k4  = (tid & 7) * 4;    // 0..28
    bf16x4_t v;
    #pragma unroll
    for (int q = 0; q < 4; ++q) v[q] = (__bf16)tile[k4 + q][n_l];

    const int n    = n0 + n_l;
    const int nb   = n / 320, rloc = n - nb * 320;
    const int kt   = k0 >> 5;
    const int lc   = (k4 >> 3) & 3, e = k4 & 7;
    const int phys = (lc + (rloc >> 1)) & 3;
    char* dst = (char*)WT + ((size_t)(nb * 256 + kt)) * 20480
              + rloc * 64 + phys * 16 + e * 2;
    *reinterpret_cast<bf16x4_t*>(dst) = v;
}

// ---------------------------------------------------------------------------
// Kernel 3: bf16 MFMA GEMM on packed tiles. BM=256 x BN=320, grid = exactly
// 256 blocks (1/CU, no tail). 512 threads = 8 waves (4m x 2n), wave tile
// 64x160. 4 LDS buffers (144 KB), prefetch distance 3, static indices.
// Waves 0-3 stage A (4 x 16B/phase), waves 4-7 stage B (5/phase).
// ---------------------------------------------------------------------------
#define BM 256
#define BN 320
#define BK 32
#define ATILE 16384
#define BTILE 20480

__global__ __launch_bounds__(512, 2) void gemm_kernel(
    const __hip_bfloat16* __restrict__ A,   // packed [32][256][16KB]
    const __hip_bfloat16* __restrict__ BT,  // packed [8][256][20KB]
    const float* __restrict__ b_inv, const float* __restrict__ g_inv,
    const float* __restrict__ be_inv,
    const float* __restrict__ b_eq,  const float* __restrict__ g_eq,
    const float* __restrict__ be_eq,
    float* __restrict__ out_inv,            // d_out: [BROWS][NINV]
    float* __restrict__ Yeq)                // ws:    [BROWS][2048]
{
    __shared__ alignas(16) __hip_bfloat16 AsBuf[4][BM * BK];  // 4 x 16 KB
    __shared__ alignas(16) __hip_bfloat16 BsBuf[4][BN * BK];  // 4 x 20 KB

    const int tid  = threadIdx.x;
    const int wave = tid >> 6;
    const int lane = tid & 63;
    const bool aWave = wave < 4;

    // 256 blocks: xcd = b%8 owns 4 contiguous m-stripes, n fastest.
    const int b    = blockIdx.x;
    const int xcd  = b & 7;
    const int slot = b >> 3;            // 0..31
    const int nb   = slot & 7;          // 0..7
    const int mb   = xcd * 4 + (slot >> 3);
    const int n0   = nb * BN;
    const int m0   = mb * BM;

    const char* pA = (const char*)A  + ((size_t)mb << 22);        // mb*4MB
    const char* pB = (const char*)BT + (size_t)nb * 256 * BTILE;  // nb*5MB

    // staging offsets (linear memcpy within a tile)
    const int aoff = wave * 4096 + lane * 16;         // waves 0-3
    const int boff = (wave - 4) * 5120 + lane * 16;   // waves 4-7

    // ds_read chunk swizzle (row-parity based, tile-term-independent)
    const int chnk = (((lane >> 4) + ((lane & 15) >> 1)) & 3) * 8;
    const int wm = (wave & 3) * 64;
    const int wn = (wave >> 2) * 160;
    const int l15 = lane & 15;

    f32x4 acc[4][10] = {};

#define ISSUE(bufi, t)                                                        \
    do {                                                                      \
        if (aWave) {                                                          \
            _Pragma("unroll")                                                 \
            for (int j = 0; j < 4; ++j)                                       \
                async_copy16(pA + (size_t)(t) * ATILE + aoff + j * 1024,      \
                             (char*)&AsBuf[bufi][0] + aoff + j * 1024);       \
        } else {                                                              \
            _Pragma("unroll")                                                 \
            for (int j = 0; j < 5; ++j)                                       \
                async_copy16(pB + (size_t)(t) * BTILE + boff + j * 1024,      \
                             (char*)&BsBuf[bufi][0] + boff + j * 1024);       \
        }                                                                     \
    } while (0)

#define COMPUTE(bufi)                                                         \
    do {                                                                      \
        bf16x8_t a_[4];                                                       \
        _Pragma("unroll")                                                     \
        for (int mt = 0; mt < 4; ++mt)                                        \
            a_[mt] = *reinterpret_cast<const bf16x8_t*>(                      \
                &AsBuf[bufi][(wm + mt * 16 + l15) * BK + chnk]);              \
        _Pragma("unroll")                                                     \
        for (int nt = 0; nt < 10; ++nt) {                                     \
            bf16x8_t b_ = *reinterpret_cast<const bf16x8_t*>(                 \
                &BsBuf[bufi][(wn + nt * 16 + l15) * BK + chnk]);              \
            _Pragma("unroll")                                                 \
            for (int mt = 0; mt < 4; ++mt)                                    \
                acc[mt][nt] = __builtin_amdgcn_mfma_f32_16x16x32_bf16(        \
                    a_[mt], b_, acc[mt][nt], 0, 0, 0);                        \
        }                                                                     \
    } while (0)

#define WAITAB(na, nb_)                                                       \
    do {                                                                      \
        if (aWave) asm volatile("s_waitcnt vmcnt(" #na ")" ::: "memory");     \
        else       asm volatile("s_waitcnt vmcnt(" #nb_ ")" ::: "memory");    \
    } while (0)

#define PHASE(bufc, bufp, t)                                                  \
    do {                                                                      \
        ISSUE(bufp, t + 3);                                                   \
        WAITAB(12, 15);                                                       \
        __builtin_amdgcn_s_barrier();                                         \
        asm volatile("" ::: "memory");                                        \
        COMPUTE(bufc);                                                        \
        asm volatile("" ::: "memory");                                        \
        __builtin_amdgcn_s_barrier();                                         \
    } while (0)

    // prologue: tiles 0,1,2 -> bufs 0,1,2
    ISSUE(0, 0);
    ISSUE(1, 1);
    ISSUE(2, 2);

    for (int i4 = 0; i4 < 63; ++i4) {
        const int t = i4 * 4;
        PHASE(0, 3, t);
        PHASE(1, 0, t + 1);
        PHASE(2, 1, t + 2);
        PHASE(3, 2, t + 3);
    }
    // tail: tiles 252..255 in bufs 0..3
    ISSUE(3, 255);
    WAITAB(12, 15);
    __builtin_amdgcn_s_barrier();
    asm volatile("" ::: "memory");
    COMPUTE(0);
    asm volatile("" ::: "memory");
    __builtin_amdgcn_s_barrier();

    WAITAB(8, 10);
    __builtin_amdgcn_s_barrier();
    asm volatile("" ::: "memory");
    COMPUTE(1);
    asm volatile("" ::: "memory");
    __builtin_amdgcn_s_barrier();

    WAITAB(4, 5);
    __builtin_amdgcn_s_barrier();
    asm volatile("" ::: "memory");
    COMPUTE(2);
    asm volatile("" ::: "memory");
    __builtin_amdgcn_s_barrier();

    asm volatile("s_waitcnt vmcnt(0)" ::: "memory");
    __builtin_amdgcn_s_barrier();
    asm volatile("" ::: "memory");
    COMPUTE(3);

    // epilogue: y = relu(g * (acc + b) / sqrt(1.001) + be), params fused
    const float RSQ = 0.9995003746877732f;
    #pragma unroll
    for (int nt = 0; nt < 10; ++nt) {
        const int gn = n0 + wn + nt * 16 + l15;
        float bbp, gg, bep;
        if (gn < NINV) {
            bbp = b_inv[gn]; gg = g_inv[gn]; bep = be_inv[gn];
        } else {
            const int e = gn - NINV, hh = e >> 10, nl = e & 1023;
            bbp = b_eq[hh * NEQ + nl]; gg = g_eq[hh * NEQ + nl]; bep = be_eq[hh * NEQ + nl];
        }
        gg *= RSQ;
        #pragma unroll
        for (int mt = 0; mt < 4; ++mt) {
            const int gmb = m0 + wm + mt * 16 + ((lane >> 4) << 2);
            #pragma unroll
            for (int rr = 0; rr < 4; ++rr) {
                float y = fmaxf(gg * (acc[mt][nt][rr] + bbp) + bep, 0.0f);
                const size_t gm = gmb + rr;
                if (gn < NINV) out_inv[gm * NINV + gn] = y;
                else           Yeq[gm * 2048 + (gn - NINV)] = y;
            }
        }
    }
#undef PHASE
#undef WAITAB
#undef COMPUTE
#undef ISSUE
}

// ---------------------------------------------------------------------------
// Kernel 4: basis recombine
// ---------------------------------------------------------------------------
__global__ __launch_bounds__(128) void eqcomb_kernel(
    const float* __restrict__ Yeq,   // [BROWS][2048]
    const float* __restrict__ V1, const float* __restrict__ V2,
    float* __restrict__ out_eq)      // [BROWS][3][128]
{
    const int row = blockIdx.x;
    const int tid = threadIdx.x;     // 128
    __shared__ float sV[2][DDIM][BAS];
    if (tid < 96) {
        const int h = tid / 48, rem = tid % 48;
        const float* V = h ? V2 : V1;
        sV[h][rem / BAS][rem % BAS] = V[(size_t)row * (DDIM * BAS) + rem];
    }
    __syncthreads();
    const int l = tid >> 6, u = tid & 63;
    const float4* y4 = reinterpret_cast<const float4*>(
        Yeq + (size_t)row * 2048 + l * 1024 + u * BAS);
    float a0 = 0.f, a1 = 0.f, a2 = 0.f;
    #pragma unroll
    for (int q = 0; q < 4; ++q) {
        float4 w = y4[q];
        const float* v0 = sV[l][0] + q * 4;
        const float* v1 = sV[l][1] + q * 4;
        const float* v2 = sV[l][2] + q * 4;
        a0 += w.x * v0[0] + w.y * v0[1] + w.z * v0[2] + w.w * v0[3];
        a1 += w.x * v1[0] + w.y * v1[1] + w.z * v1[2] + w.w * v1[3];
        a2 += w.x * v2[0] + w.y * v2[1] + w.z * v2[2] + w.w * v2[3];
    }
    float* o = out_eq + (size_t)row * (DDIM * 128);
    o[0 * 128 + l * 64 + u] = a0;
    o[1 * 128 + l * 64 + u] = a1;
    o[2 * 128 + l * 64 + u] = a2;
}

// ---------------------------------------------------------------------------
extern "C" void kernel_launch(void* const* d_in, const int* in_sizes, int n_in,
                              void* d_out, int out_size, void* d_ws, size_t ws_size,
                              hipStream_t stream) {
    const float* t1    = (const float*)d_in[0];
    const float* t2    = (const float*)d_in[1];
    const float* u1    = (const float*)d_in[2];
    const float* u2    = (const float*)d_in[3];
    const float* V1    = (const float*)d_in[4];
    const float* V2    = (const float*)d_in[5];
    const float* W_inv = (const float*)d_in[6];
    const float* b_inv = (const float*)d_in[7];
    const float* g_inv = (const float*)d_in[8];
    const float* be_inv= (const float*)d_in[9];
    const float* W_eq  = (const float*)d_in[10];
    const float* b_eq  = (const float*)d_in[11];
    const float* g_eq  = (const float*)d_in[12];
    const float* be_eq = (const float*)d_in[13];
    float* out = (float*)d_out;

    // workspace layout (bytes)
    char* ws = (char*)d_ws;
    __hip_bfloat16* feats = (__hip_bfloat16*)(ws);                       // 134,217,728 (packed)
    __hip_bfloat16* WT    = (__hip_bfloat16*)(ws + 134217728);           //  41,943,040 (packed)
    float*          Yeq   = (float*)(ws + 176160768);                    //  67,108,864

    float* out_inv = out;                                  // [8192][512]
    float* out_eq  = out + (size_t)BROWS * NINV;           // [8192][3][128]

    hipLaunchKernelGGL(feats_kernel, dim3(BROWS), dim3(256), 0, stream,
                       t1, t2, u1, u2, feats);
    hipLaunchKernelGGL(wt_kernel, dim3(NTOT / 32, KF / 32), dim3(256), 0, stream,
                       W_inv, W_eq, WT);
    hipLaunchKernelGGL(gemm_kernel, dim3((NTOT / BN) * (BROWS / BM)), dim3(512), 0, stream,
                       feats, WT, b_inv, g_inv, be_inv, b_eq, g_eq, be_eq,
                       out_inv, Yeq);
    hipLaunchKernelGGL(eqcomb_kernel, dim3(BROWS), dim3(128), 0, stream,
                       Yeq, V1, V2, out_eq);
}